// Round 1
// baseline (4319.055 us; speedup 1.0000x reference)
//
#include <hip/hip_runtime.h>
#include <hip/hip_bf16.h>

#define DIM 256
#define QK 64
#define PD 128
#define HID 512
#define NPX 4096          // 64*64 pixels per image
#define NB 16
#define SCALE 0.125f      // 64^-0.5
#define GN_EPS 1e-5f

// ---------------- GroupNorm stats ----------------
__global__ __launch_bounds__(256) void gn_part_kernel(const float* __restrict__ x, float* __restrict__ part) {
    int chunk = blockIdx.x, b = blockIdx.y;
    const float* xp = x + (size_t)b * (DIM * NPX) + (size_t)chunk * 16384;
    float s = 0.f, ss = 0.f;
    for (int i = threadIdx.x; i < 16384; i += 256) { float v = xp[i]; s += v; ss += v * v; }
    for (int off = 32; off > 0; off >>= 1) { s += __shfl_down(s, off); ss += __shfl_down(ss, off); }
    __shared__ float red[8];
    int w = threadIdx.x >> 6;
    if ((threadIdx.x & 63) == 0) { red[w * 2] = s; red[w * 2 + 1] = ss; }
    __syncthreads();
    if (threadIdx.x == 0) {
        float S = red[0] + red[2] + red[4] + red[6];
        float SS = red[1] + red[3] + red[5] + red[7];
        part[(b * 64 + chunk) * 2] = S;
        part[(b * 64 + chunk) * 2 + 1] = SS;
    }
}

__global__ __launch_bounds__(256) void gn_final_kernel(const float* __restrict__ part,
                                                       const float* __restrict__ gn_w, const float* __restrict__ gn_b,
                                                       float* __restrict__ Aarr, float* __restrict__ Barr) {
    int b = blockIdx.x;
    float s = 0.f, ss = 0.f;
    if (threadIdx.x < 64) {
        s = part[(b * 64 + threadIdx.x) * 2];
        ss = part[(b * 64 + threadIdx.x) * 2 + 1];
        for (int off = 32; off > 0; off >>= 1) { s += __shfl_down(s, off); ss += __shfl_down(ss, off); }
    }
    __shared__ float sh[2];
    if (threadIdx.x == 0) {
        const float invN = 1.f / (float)(DIM * NPX);
        float mu = s * invN;
        float var = ss * invN - mu * mu;
        sh[0] = mu; sh[1] = rsqrtf(var + GN_EPS);
    }
    __syncthreads();
    float mu = sh[0], rstd = sh[1];
    int c = threadIdx.x;
    float g = gn_w[c] * rstd;
    Aarr[b * 256 + c] = g;
    Barr[b * 256 + c] = gn_b[c] - mu * g;
}

// ---------------- conv3x3 (GN affine fused on input load) ----------------
// block: 256 thr; tile: 32 oc x (4 rows x 64 cols); thread: 4 oc x 8 px
__global__ __launch_bounds__(256) void conv3_kernel(const float* __restrict__ x,
                                                    const float* __restrict__ Aarr, const float* __restrict__ Barr,
                                                    const float* __restrict__ w_in,
                                                    const float* __restrict__ s_in, const float* __restrict__ b_in,
                                                    float* __restrict__ t) {
    int g = blockIdx.x;      // 0..11 : oc group of 32
    int rg = blockIdx.y;     // 0..15 : row group of 4
    int b = blockIdx.z;
    int tid = threadIdx.x;
    int ocg = tid & 7, pg = tid >> 3;
    int r = pg >> 3, cb = pg & 7;
    __shared__ float inS[8 * 6 * 68];
    __shared__ float wS[32 * 73];
    float acc[4][8];
#pragma unroll
    for (int o = 0; o < 4; o++)
#pragma unroll
        for (int p = 0; p < 8; p++) acc[o][p] = 0.f;
    int y0 = rg * 4;
    const float* xb = x + ((size_t)b << 20);
    const float* Ab = Aarr + b * 256;
    const float* Bb = Barr + b * 256;
    for (int cc0 = 0; cc0 < 256; cc0 += 8) {
        __syncthreads();
        for (int i = tid; i < 8 * 6 * 66; i += 256) {
            int c = i / 396; int rem = i - c * 396;
            int rr = rem / 66; int col = rem - rr * 66 - 1;
            int y = y0 - 1 + rr;
            float v = 0.f;
            int ch = cc0 + c;
            if (y >= 0 && y < 64 && col >= 0 && col < 64)
                v = fmaf(xb[((size_t)ch << 12) + y * 64 + col], Ab[ch], Bb[ch]);
            inS[(c * 6 + rr) * 68 + (col + 1)] = v;
        }
        for (int i = tid; i < 32 * 72; i += 256) {
            int oc = i / 72; int rem = i - oc * 72;
            wS[oc * 73 + rem] = w_in[((size_t)(g * 32 + oc) * 256 + (cc0 + rem / 9)) * 9 + rem % 9];
        }
        __syncthreads();
#pragma unroll 2
        for (int c = 0; c < 8; c++) {
#pragma unroll
            for (int dy = 0; dy < 3; dy++) {
                float v[10];
                const float* ip = &inS[(c * 6 + r + dy) * 68 + cb * 8];
#pragma unroll
                for (int j = 0; j < 10; j++) v[j] = ip[j];
#pragma unroll
                for (int o = 0; o < 4; o++) {
                    const float* wp = &wS[(ocg * 4 + o) * 73 + c * 9 + dy * 3];
                    float w0 = wp[0], w1 = wp[1], w2 = wp[2];
#pragma unroll
                    for (int px = 0; px < 8; px++)
                        acc[o][px] = fmaf(w0, v[px], fmaf(w1, v[px + 1], fmaf(w2, v[px + 2], acc[o][px])));
                }
            }
        }
    }
#pragma unroll
    for (int o = 0; o < 4; o++) {
        int oc = g * 32 + ocg * 4 + o;
        float sc = s_in[oc], bi = b_in[oc];
        size_t base = (((size_t)b * 384 + oc) << 12) + (size_t)(y0 + r) * 64 + cb * 8;
        float4 v0 = make_float4(fmaf(acc[o][0], sc, bi), fmaf(acc[o][1], sc, bi), fmaf(acc[o][2], sc, bi), fmaf(acc[o][3], sc, bi));
        float4 v1 = make_float4(fmaf(acc[o][4], sc, bi), fmaf(acc[o][5], sc, bi), fmaf(acc[o][6], sc, bi), fmaf(acc[o][7], sc, bi));
        *(float4*)&t[base] = v0;
        *(float4*)&t[base + 4] = v1;
    }
}

// ---------------- depthwise 2x2 stride-2 for k and v ----------------
__global__ __launch_bounds__(256) void dw_kernel(const float* __restrict__ t,
                                                 const float* __restrict__ w_k, const float* __restrict__ s_k, const float* __restrict__ b_k,
                                                 const float* __restrict__ w_v, const float* __restrict__ s_v, const float* __restrict__ b_v,
                                                 float* __restrict__ kd, float* __restrict__ vd) {
    int gid = blockIdx.x * 256 + threadIdx.x;
    if (gid < (1 << 20)) {
        int b = gid >> 16, c = (gid >> 10) & 63, m = gid & 1023;
        int yo = m >> 5, xo = m & 31;
        const float* src = t + (((size_t)b * 384 + 64 + c) << 12) + (size_t)(yo * 2) * 64 + xo * 2;
        float v = w_k[c * 4] * src[0] + w_k[c * 4 + 1] * src[1] + w_k[c * 4 + 2] * src[64] + w_k[c * 4 + 3] * src[65];
        kd[gid] = fmaf(v, s_k[c], b_k[c]);
    } else {
        int gg = gid - (1 << 20);
        int b = gg >> 17, c = (gg >> 10) & 127, m = gg & 1023;
        int yo = m >> 5, xo = m & 31;
        const float* src = t + (((size_t)b * 384 + 128 + c) << 12) + (size_t)(yo * 2) * 64 + xo * 2;
        float v = w_v[c * 4] * src[0] + w_v[c * 4 + 1] * src[1] + w_v[c * 4 + 2] * src[64] + w_v[c * 4 + 3] * src[65];
        vd[gg] = fmaf(v, s_v[c], b_v[c]);
    }
}

// ---------------- flash attention: 64 q-rows per block, m-tiles of 32 ----------------
__global__ __launch_bounds__(256) void attn_kernel(const float* __restrict__ t, const float* __restrict__ kd,
                                                   const float* __restrict__ vd, float* __restrict__ a_out) {
    int nt = blockIdx.x, b = blockIdx.y;
    int tid = threadIdx.x;
    __shared__ float Qs[64 * 64];       // [c][n]
    __shared__ float Ks[64 * 32];       // [c][m]
    __shared__ float Vs[128 * 34];      // [p][m], stride 34
    __shared__ float Ps[64 * 33];       // [n][m], stride 33
    const float* tq = t + (((size_t)b * 384) << 12) + nt * 64;
    for (int i = tid; i < 4096; i += 256) {
        int c = i >> 6, nl = i & 63;
        Qs[c * 64 + nl] = tq[((size_t)c << 12) + nl];
    }
    int n = tid >> 2, pq = tid & 3;
    float m_run = -1e30f, l_run = 0.f;
    float O[32];
#pragma unroll
    for (int k = 0; k < 32; k++) O[k] = 0.f;
    const float* kb = kd + ((size_t)(b * 64) << 10);
    const float* vb = vd + ((size_t)(b * 128) << 10);
    for (int mt = 0; mt < 32; mt++) {
        __syncthreads();
        for (int i = tid; i < 64 * 32; i += 256) {
            int c = i >> 5, ml = i & 31;
            Ks[c * 32 + ml] = kb[(c << 10) + mt * 32 + ml];
        }
        for (int i = tid; i < 128 * 32; i += 256) {
            int p = i >> 5, ml = i & 31;
            Vs[p * 34 + ml] = vb[(p << 10) + mt * 32 + ml];
        }
        __syncthreads();
        float s[8];
#pragma unroll
        for (int j = 0; j < 8; j++) s[j] = 0.f;
        for (int c = 0; c < 64; c++) {
            float qv = Qs[c * 64 + n];
#pragma unroll
            for (int j = 0; j < 8; j++) s[j] = fmaf(qv, Ks[c * 32 + pq * 8 + j], s[j]);
        }
        float tmax = -1e30f;
#pragma unroll
        for (int j = 0; j < 8; j++) { s[j] *= SCALE; tmax = fmaxf(tmax, s[j]); }
        tmax = fmaxf(tmax, __shfl_xor(tmax, 1));
        tmax = fmaxf(tmax, __shfl_xor(tmax, 2));
        float newm = fmaxf(m_run, tmax);
        float fac = __expf(m_run - newm);
        float psum = 0.f;
#pragma unroll
        for (int j = 0; j < 8; j++) { s[j] = __expf(s[j] - newm); psum += s[j]; }
        psum += __shfl_xor(psum, 1);
        psum += __shfl_xor(psum, 2);
        l_run = fmaf(l_run, fac, psum);
        m_run = newm;
#pragma unroll
        for (int j = 0; j < 8; j++) Ps[n * 33 + pq * 8 + j] = s[j];
#pragma unroll
        for (int k = 0; k < 32; k++) O[k] *= fac;
        __syncthreads();
#pragma unroll
        for (int mc = 0; mc < 4; mc++) {
            float pr[8];
#pragma unroll
            for (int j = 0; j < 8; j++) pr[j] = Ps[n * 33 + mc * 8 + j];
#pragma unroll
            for (int k = 0; k < 32; k++) {
                int p = pq + 4 * k;
#pragma unroll
                for (int j = 0; j < 8; j++) O[k] = fmaf(Vs[p * 34 + mc * 8 + j], pr[j], O[k]);
            }
        }
    }
    float inv = 1.f / l_run;
    float* ab = a_out + (((size_t)b * 128) << 12) + nt * 64 + n;
#pragma unroll
    for (int k = 0; k < 32; k++) {
        int p = pq + 4 * k;
        ab[(size_t)p << 12] = O[k] * inv;
    }
}

// ---------------- cat(relu) 1x1 conv + residual -> x1 (into out) ----------------
__global__ __launch_bounds__(256) void catconv_kernel(const float* __restrict__ a_in, const float* __restrict__ t,
                                                      const float* __restrict__ x, const float* __restrict__ w_out,
                                                      const float* __restrict__ s_out, const float* __restrict__ b_out,
                                                      float* __restrict__ out) {
    int pxt = blockIdx.x, cot = blockIdx.y, b = blockIdx.z;
    int tid = threadIdx.x;
    __shared__ float Xs[16 * 64];
    __shared__ float Ws[64 * 17];
    int tc = tid & 15, tr = tid >> 4;
    float acc[4][4];
#pragma unroll
    for (int o = 0; o < 4; o++)
#pragma unroll
        for (int j = 0; j < 4; j++) acc[o][j] = 0.f;
    int px0 = pxt * 64, co0 = cot * 64;
    for (int ch = 0; ch < 16; ch++) {
        __syncthreads();
        int ci0 = ch * 16;
        int i = tid;
#pragma unroll
        for (int rep = 0; rep < 4; rep++, i += 256) {
            int cic = i >> 6, pxl = i & 63;
            int ci = ci0 + cic;
            float val = (ci < 128) ? a_in[(((size_t)b * 128 + ci) << 12) + px0 + pxl]
                                   : t[(((size_t)b * 384 + 128 + ci) << 12) + px0 + pxl];
            Xs[cic * 64 + pxl] = fmaxf(val, 0.f);
        }
        i = tid;
#pragma unroll
        for (int rep = 0; rep < 4; rep++, i += 256) {
            int cor = i >> 4, cic = i & 15;
            Ws[cor * 17 + cic] = w_out[(size_t)(co0 + cor) * 256 + ci0 + cic];
        }
        __syncthreads();
#pragma unroll
        for (int cic = 0; cic < 16; cic++) {
            float av[4], bv[4];
#pragma unroll
            for (int o = 0; o < 4; o++) av[o] = Ws[(tr * 4 + o) * 17 + cic];
#pragma unroll
            for (int j = 0; j < 4; j++) bv[j] = Xs[cic * 64 + tc * 4 + j];
#pragma unroll
            for (int o = 0; o < 4; o++)
#pragma unroll
                for (int j = 0; j < 4; j++) acc[o][j] = fmaf(av[o], bv[j], acc[o][j]);
        }
    }
#pragma unroll
    for (int o = 0; o < 4; o++) {
        int co = co0 + tr * 4 + o;
        float sc = s_out[co], bi = b_out[co];
        size_t base = (((size_t)b * 256 + co) << 12) + px0 + tc * 4;
#pragma unroll
        for (int j = 0; j < 4; j++)
            out[base + j] = x[base + j] + fmaf(acc[o][j], sc, bi);
    }
}

// ---------------- FFN1: h = relu(bn(W1 @ x1)), bf16 out ----------------
__global__ __launch_bounds__(256) void ffn1_kernel(const float* __restrict__ x1, const float* __restrict__ w1,
                                                   const float* __restrict__ s1, const float* __restrict__ b1,
                                                   __hip_bfloat16* __restrict__ h) {
    int pxt = blockIdx.x, cot = blockIdx.y, b = blockIdx.z;
    int tid = threadIdx.x;
    __shared__ float Xs[16 * 64];
    __shared__ float Ws[64 * 17];
    int tc = tid & 15, tr = tid >> 4;
    float acc[4][4];
#pragma unroll
    for (int o = 0; o < 4; o++)
#pragma unroll
        for (int j = 0; j < 4; j++) acc[o][j] = 0.f;
    int px0 = pxt * 64, co0 = cot * 64;
    for (int ch = 0; ch < 16; ch++) {
        __syncthreads();
        int ci0 = ch * 16;
        int i = tid;
#pragma unroll
        for (int rep = 0; rep < 4; rep++, i += 256) {
            int cic = i >> 6, pxl = i & 63;
            Xs[cic * 64 + pxl] = x1[(((size_t)b * 256 + ci0 + cic) << 12) + px0 + pxl];
        }
        i = tid;
#pragma unroll
        for (int rep = 0; rep < 4; rep++, i += 256) {
            int cor = i >> 4, cic = i & 15;
            Ws[cor * 17 + cic] = w1[(size_t)(co0 + cor) * 256 + ci0 + cic];
        }
        __syncthreads();
#pragma unroll
        for (int cic = 0; cic < 16; cic++) {
            float av[4], bv[4];
#pragma unroll
            for (int o = 0; o < 4; o++) av[o] = Ws[(tr * 4 + o) * 17 + cic];
#pragma unroll
            for (int j = 0; j < 4; j++) bv[j] = Xs[cic * 64 + tc * 4 + j];
#pragma unroll
            for (int o = 0; o < 4; o++)
#pragma unroll
                for (int j = 0; j < 4; j++) acc[o][j] = fmaf(av[o], bv[j], acc[o][j]);
        }
    }
#pragma unroll
    for (int o = 0; o < 4; o++) {
        int hc = co0 + tr * 4 + o;
        float sc = s1[hc], bi = b1[hc];
        size_t base = (((size_t)b * 512 + hc) << 12) + px0 + tc * 4;
#pragma unroll
        for (int j = 0; j < 4; j++)
            h[base + j] = __float2bfloat16(fmaxf(fmaf(acc[o][j], sc, bi), 0.f));
    }
}

// ---------------- FFN2: out = x1 + bn(W2 @ h) ----------------
__global__ __launch_bounds__(256) void ffn2_kernel(const __hip_bfloat16* __restrict__ h, const float* __restrict__ w2,
                                                   const float* __restrict__ s2, const float* __restrict__ b2,
                                                   float* __restrict__ out) {
    int pxt = blockIdx.x, cot = blockIdx.y, b = blockIdx.z;
    int tid = threadIdx.x;
    __shared__ float Xs[16 * 64];
    __shared__ float Ws[64 * 17];
    int tc = tid & 15, tr = tid >> 4;
    float acc[4][4];
#pragma unroll
    for (int o = 0; o < 4; o++)
#pragma unroll
        for (int j = 0; j < 4; j++) acc[o][j] = 0.f;
    int px0 = pxt * 64, co0 = cot * 64;
    for (int ch = 0; ch < 32; ch++) {
        __syncthreads();
        int ci0 = ch * 16;
        int i = tid;
#pragma unroll
        for (int rep = 0; rep < 4; rep++, i += 256) {
            int cic = i >> 6, pxl = i & 63;
            Xs[cic * 64 + pxl] = __bfloat162float(h[(((size_t)b * 512 + ci0 + cic) << 12) + px0 + pxl]);
        }
        i = tid;
#pragma unroll
        for (int rep = 0; rep < 4; rep++, i += 256) {
            int cor = i >> 4, cic = i & 15;
            Ws[cor * 17 + cic] = w2[(size_t)(co0 + cor) * 512 + ci0 + cic];
        }
        __syncthreads();
#pragma unroll
        for (int cic = 0; cic < 16; cic++) {
            float av[4], bv[4];
#pragma unroll
            for (int o = 0; o < 4; o++) av[o] = Ws[(tr * 4 + o) * 17 + cic];
#pragma unroll
            for (int j = 0; j < 4; j++) bv[j] = Xs[cic * 64 + tc * 4 + j];
#pragma unroll
            for (int o = 0; o < 4; o++)
#pragma unroll
                for (int j = 0; j < 4; j++) acc[o][j] = fmaf(av[o], bv[j], acc[o][j]);
        }
    }
#pragma unroll
    for (int o = 0; o < 4; o++) {
        int co = co0 + tr * 4 + o;
        float sc = s2[co], bi = b2[co];
        size_t base = (((size_t)b * 256 + co) << 12) + px0 + tc * 4;
#pragma unroll
        for (int j = 0; j < 4; j++)
            out[base + j] = out[base + j] + fmaf(acc[o][j], sc, bi);
    }
}

extern "C" void kernel_launch(void* const* d_in, const int* in_sizes, int n_in,
                              void* d_out, int out_size, void* d_ws, size_t ws_size,
                              hipStream_t stream) {
    const float* x    = (const float*)d_in[0];
    const float* gn_w = (const float*)d_in[1];
    const float* gn_b = (const float*)d_in[2];
    const float* w_in = (const float*)d_in[3];
    const float* s_in = (const float*)d_in[4];
    const float* b_in = (const float*)d_in[5];
    const float* w_k  = (const float*)d_in[6];
    const float* s_k  = (const float*)d_in[7];
    const float* b_k  = (const float*)d_in[8];
    const float* w_v  = (const float*)d_in[9];
    const float* s_v  = (const float*)d_in[10];
    const float* b_v  = (const float*)d_in[11];
    const float* w_out= (const float*)d_in[12];
    const float* s_out= (const float*)d_in[13];
    const float* b_out= (const float*)d_in[14];
    const float* w1   = (const float*)d_in[15];
    const float* s1   = (const float*)d_in[16];
    const float* b1   = (const float*)d_in[17];
    const float* w2   = (const float*)d_in[18];
    const float* s2   = (const float*)d_in[19];
    const float* b2   = (const float*)d_in[20];
    float* out = (float*)d_out;
    float* ws = (float*)d_ws;

    float* part = ws;                         // 2048 floats
    float* Aarr = ws + 2048;                  // 4096
    float* Barr = ws + 6144;                  // 4096
    float* t    = ws + 10240;                 // 16*384*4096 = 25165824
    float* kd   = t + 25165824;               // 16*64*1024  = 1048576
    float* vd   = kd + 1048576;               // 16*128*1024 = 2097152
    float* a    = vd + 2097152;               // 16*128*4096 = 8388608
    __hip_bfloat16* h = (__hip_bfloat16*)(a + 8388608); // 16*512*4096 bf16

    gn_part_kernel<<<dim3(64, 16), 256, 0, stream>>>(x, part);
    gn_final_kernel<<<16, 256, 0, stream>>>(part, gn_w, gn_b, Aarr, Barr);
    conv3_kernel<<<dim3(12, 16, 16), 256, 0, stream>>>(x, Aarr, Barr, w_in, s_in, b_in, t);
    dw_kernel<<<12288, 256, 0, stream>>>(t, w_k, s_k, b_k, w_v, s_v, b_v, kd, vd);
    attn_kernel<<<dim3(64, 16), 256, 0, stream>>>(t, kd, vd, a);
    catconv_kernel<<<dim3(64, 4, 16), 256, 0, stream>>>(a, t, x, w_out, s_out, b_out, out);
    ffn1_kernel<<<dim3(64, 8, 16), 256, 0, stream>>>(out, w1, s1, b1, h);
    ffn2_kernel<<<dim3(64, 4, 16), 256, 0, stream>>>(h, w2, s2, b2, out);
}

// Round 2
// 2455.803 us; speedup vs baseline: 1.7587x; 1.7587x over previous
//
#include <hip/hip_runtime.h>
#include <hip/hip_bf16.h>

#define DIM 256
#define QK 64
#define PD 128
#define HID 512
#define NPX 4096          // 64*64 pixels per image
#define NB 16
#define SCALE 0.125f      // 64^-0.5
#define GN_EPS 1e-5f

typedef short bf16x8 __attribute__((ext_vector_type(8)));
typedef float f32x4 __attribute__((ext_vector_type(4)));
#define MFMA16(a, b, c) __builtin_amdgcn_mfma_f32_16x16x32_bf16(a, b, c, 0, 0, 0)

__device__ __forceinline__ unsigned f2b(float f) {
    unsigned u = __float_as_uint(f);
    return (u + 0x7fffu + ((u >> 16) & 1u)) >> 16;  // RNE bf16, as low 16 bits
}

// ---------------- GroupNorm stats ----------------
__global__ __launch_bounds__(256) void gn_part_kernel(const float* __restrict__ x, float* __restrict__ part) {
    int chunk = blockIdx.x, b = blockIdx.y;
    const float* xp = x + (size_t)b * (DIM * NPX) + (size_t)chunk * 16384;
    float s = 0.f, ss = 0.f;
    for (int i = threadIdx.x; i < 16384; i += 256) { float v = xp[i]; s += v; ss += v * v; }
    for (int off = 32; off > 0; off >>= 1) { s += __shfl_down(s, off); ss += __shfl_down(ss, off); }
    __shared__ float red[8];
    int w = threadIdx.x >> 6;
    if ((threadIdx.x & 63) == 0) { red[w * 2] = s; red[w * 2 + 1] = ss; }
    __syncthreads();
    if (threadIdx.x == 0) {
        float S = red[0] + red[2] + red[4] + red[6];
        float SS = red[1] + red[3] + red[5] + red[7];
        part[(b * 64 + chunk) * 2] = S;
        part[(b * 64 + chunk) * 2 + 1] = SS;
    }
}

__global__ __launch_bounds__(256) void gn_final_kernel(const float* __restrict__ part,
                                                       const float* __restrict__ gn_w, const float* __restrict__ gn_b,
                                                       float* __restrict__ Aarr, float* __restrict__ Barr) {
    int b = blockIdx.x;
    float s = 0.f, ss = 0.f;
    if (threadIdx.x < 64) {
        s = part[(b * 64 + threadIdx.x) * 2];
        ss = part[(b * 64 + threadIdx.x) * 2 + 1];
        for (int off = 32; off > 0; off >>= 1) { s += __shfl_down(s, off); ss += __shfl_down(ss, off); }
    }
    __shared__ float sh[2];
    if (threadIdx.x == 0) {
        const float invN = 1.f / (float)(DIM * NPX);
        float mu = s * invN;
        float var = ss * invN - mu * mu;
        sh[0] = mu; sh[1] = rsqrtf(var + GN_EPS);
    }
    __syncthreads();
    float mu = sh[0], rstd = sh[1];
    int c = threadIdx.x;
    float g = gn_w[c] * rstd;
    Aarr[b * 256 + c] = g;
    Barr[b * 256 + c] = gn_b[c] - mu * g;
}

// ---------------- conv3x3 (GN affine fused on input load) ----------------
__global__ __launch_bounds__(256) void conv3_kernel(const float* __restrict__ x,
                                                    const float* __restrict__ Aarr, const float* __restrict__ Barr,
                                                    const float* __restrict__ w_in,
                                                    const float* __restrict__ s_in, const float* __restrict__ b_in,
                                                    float* __restrict__ t) {
    int g = blockIdx.x;      // 0..11 : oc group of 32
    int rg = blockIdx.y;     // 0..15 : row group of 4
    int b = blockIdx.z;
    int tid = threadIdx.x;
    int ocg = tid & 7, pg = tid >> 3;
    int r = pg >> 3, cb = pg & 7;
    __shared__ float inS[8 * 6 * 68];
    __shared__ float wS[32 * 73];
    float acc[4][8];
#pragma unroll
    for (int o = 0; o < 4; o++)
#pragma unroll
        for (int p = 0; p < 8; p++) acc[o][p] = 0.f;
    int y0 = rg * 4;
    const float* xb = x + ((size_t)b << 20);
    const float* Ab = Aarr + b * 256;
    const float* Bb = Barr + b * 256;
    for (int cc0 = 0; cc0 < 256; cc0 += 8) {
        __syncthreads();
        for (int i = tid; i < 8 * 6 * 66; i += 256) {
            int c = i / 396; int rem = i - c * 396;
            int rr = rem / 66; int col = rem - rr * 66 - 1;
            int y = y0 - 1 + rr;
            float v = 0.f;
            int ch = cc0 + c;
            if (y >= 0 && y < 64 && col >= 0 && col < 64)
                v = fmaf(xb[((size_t)ch << 12) + y * 64 + col], Ab[ch], Bb[ch]);
            inS[(c * 6 + rr) * 68 + (col + 1)] = v;
        }
        for (int i = tid; i < 32 * 72; i += 256) {
            int oc = i / 72; int rem = i - oc * 72;
            wS[oc * 73 + rem] = w_in[((size_t)(g * 32 + oc) * 256 + (cc0 + rem / 9)) * 9 + rem % 9];
        }
        __syncthreads();
#pragma unroll 2
        for (int c = 0; c < 8; c++) {
#pragma unroll
            for (int dy = 0; dy < 3; dy++) {
                float v[10];
                const float* ip = &inS[(c * 6 + r + dy) * 68 + cb * 8];
#pragma unroll
                for (int j = 0; j < 10; j++) v[j] = ip[j];
#pragma unroll
                for (int o = 0; o < 4; o++) {
                    const float* wp = &wS[(ocg * 4 + o) * 73 + c * 9 + dy * 3];
                    float w0 = wp[0], w1 = wp[1], w2 = wp[2];
#pragma unroll
                    for (int px = 0; px < 8; px++)
                        acc[o][px] = fmaf(w0, v[px], fmaf(w1, v[px + 1], fmaf(w2, v[px + 2], acc[o][px])));
                }
            }
        }
    }
#pragma unroll
    for (int o = 0; o < 4; o++) {
        int oc = g * 32 + ocg * 4 + o;
        float sc = s_in[oc], bi = b_in[oc];
        size_t base = (((size_t)b * 384 + oc) << 12) + (size_t)(y0 + r) * 64 + cb * 8;
        float4 v0 = make_float4(fmaf(acc[o][0], sc, bi), fmaf(acc[o][1], sc, bi), fmaf(acc[o][2], sc, bi), fmaf(acc[o][3], sc, bi));
        float4 v1 = make_float4(fmaf(acc[o][4], sc, bi), fmaf(acc[o][5], sc, bi), fmaf(acc[o][6], sc, bi), fmaf(acc[o][7], sc, bi));
        *(float4*)&t[base] = v0;
        *(float4*)&t[base + 4] = v1;
    }
}

// ---------------- depthwise 2x2 stride-2 for k and v (bf16 outputs for MFMA attn) ----------------
// kd_t: [B][1024 m][64 c] bf16 ; vd_b: [B][128 p][1024 m] bf16
__global__ __launch_bounds__(256) void dw_kernel(const float* __restrict__ t,
                                                 const float* __restrict__ w_k, const float* __restrict__ s_k, const float* __restrict__ b_k,
                                                 const float* __restrict__ w_v, const float* __restrict__ s_v, const float* __restrict__ b_v,
                                                 unsigned short* __restrict__ kd_t, unsigned short* __restrict__ vd_b) {
    int gid = blockIdx.x * 256 + threadIdx.x;
    if (gid < (1 << 20)) {
        int b = gid >> 16, c = (gid >> 10) & 63, m = gid & 1023;
        int yo = m >> 5, xo = m & 31;
        const float* src = t + (((size_t)b * 384 + 64 + c) << 12) + (size_t)(yo * 2) * 64 + xo * 2;
        float v = w_k[c * 4] * src[0] + w_k[c * 4 + 1] * src[1] + w_k[c * 4 + 2] * src[64] + w_k[c * 4 + 3] * src[65];
        kd_t[((size_t)(b * 1024 + m) << 6) + c] = (unsigned short)f2b(fmaf(v, s_k[c], b_k[c]));
    } else {
        int gg = gid - (1 << 20);
        int b = gg >> 17, c = (gg >> 10) & 127, m = gg & 1023;
        int yo = m >> 5, xo = m & 31;
        const float* src = t + (((size_t)b * 384 + 128 + c) << 12) + (size_t)(yo * 2) * 64 + xo * 2;
        float v = w_v[c * 4] * src[0] + w_v[c * 4 + 1] * src[1] + w_v[c * 4 + 2] * src[64] + w_v[c * 4 + 3] * src[65];
        vd_b[gg] = (unsigned short)f2b(fmaf(v, s_v[c], b_v[c]));
    }
}

// ---------------- q transpose: t ch 0..63 [c][n] -> q_t [n][c] bf16 ----------------
__global__ __launch_bounds__(256) void qt_kernel(const float* __restrict__ t, unsigned short* __restrict__ q_t) {
    int nt = blockIdx.x, b = blockIdx.y;
    int tid = threadIdx.x;
    __shared__ float tile[64][65];
    const float* tb = t + (((size_t)b * 384) << 12) + nt * 64;
    for (int i = tid; i < 4096; i += 256) {
        int c = i >> 6, nl = i & 63;
        tile[c][nl] = tb[((size_t)c << 12) + nl];
    }
    __syncthreads();
    unsigned short* qb = q_t + (((size_t)b * 4096 + nt * 64) << 6);
    for (int i = tid; i < 4096; i += 256) {
        int n = i >> 6, c = i & 63;
        qb[((size_t)n << 6) + c] = (unsigned short)f2b(tile[c][n]);
    }
}

// ---------------- MFMA flash attention ----------------
// Per wave: 32 q-rows (2 n-frags of 16), K=64, loop 16 m-tiles of 64.
// S' = mfma(K^T, Q): D rows = m (lane-local), cols = n  -> softmax needs only shfl_xor(16/32).
// P exchanged in-register to B-operand layout for PV = mfma(V, P).
__global__ __launch_bounds__(256) void attn_mfma_kernel(const unsigned short* __restrict__ q_t,
                                                        const unsigned short* __restrict__ kd_t,
                                                        const unsigned short* __restrict__ vd_b,
                                                        float* __restrict__ a_out) {
    int tid = threadIdx.x;
    int wid = tid >> 6, lane = tid & 63;
    int g = lane >> 4, l15 = lane & 15;
    int b = blockIdx.y;
    int n0 = (blockIdx.x * 4 + wid) * 32;

    // Q B-frags: qf[nf][kc], lane holds col n=n0+16nf+l15, k c = kc*32+8g..+7
    bf16x8 qf[2][2];
#pragma unroll
    for (int nf = 0; nf < 2; nf++)
#pragma unroll
        for (int kc = 0; kc < 2; kc++)
            qf[nf][kc] = *(const bf16x8*)(q_t + (((size_t)b * 4096 + n0 + 16 * nf + l15) << 6) + kc * 32 + g * 8);

    f32x4 O[8][2];
#pragma unroll
    for (int pt = 0; pt < 8; pt++)
#pragma unroll
        for (int nf = 0; nf < 2; nf++)
#pragma unroll
            for (int r = 0; r < 4; r++) O[pt][nf][r] = 0.f;
    float mr[2] = {-1e30f, -1e30f}, lr[2] = {0.f, 0.f};

    const unsigned short* kb = kd_t + ((size_t)b << 16);         // [1024][64]
    const unsigned short* vb = vd_b + ((size_t)(b * 128) << 10); // [128][1024]

    union BU { unsigned u[4]; bf16x8 v; };

    for (int mt = 0; mt < 16; mt++) {
        int m0 = mt * 64;
        // ---- QK^T: S'[m][n] ----
        f32x4 sp[4][2];
#pragma unroll
        for (int f = 0; f < 4; f++)
#pragma unroll
            for (int nf = 0; nf < 2; nf++)
#pragma unroll
                for (int r = 0; r < 4; r++) sp[f][nf][r] = 0.f;
#pragma unroll
        for (int f = 0; f < 4; f++) {
#pragma unroll
            for (int kc = 0; kc < 2; kc++) {
                bf16x8 kf = *(const bf16x8*)(kb + (((size_t)(m0 + 16 * f + l15)) << 6) + kc * 32 + g * 8);
                sp[f][0] = MFMA16(kf, qf[0][kc], sp[f][0]);
                sp[f][1] = MFMA16(kf, qf[1][kc], sp[f][1]);
            }
        }
        // ---- online softmax + pack + exchange, per n-frag ----
        BU Bp[2][2];  // [nf][kc]
        int srcA = l15 + ((g & 1) << 5);
        int srcB = srcA + 16;
        bool hi = (g >> 1) != 0;
#pragma unroll
        for (int nf = 0; nf < 2; nf++) {
            float tmax = -1e30f;
#pragma unroll
            for (int f = 0; f < 4; f++)
#pragma unroll
                for (int r = 0; r < 4; r++) tmax = fmaxf(tmax, sp[f][nf][r]);
            tmax = fmaxf(tmax, __shfl_xor(tmax, 16));
            tmax = fmaxf(tmax, __shfl_xor(tmax, 32));
            float newm = fmaxf(mr[nf], tmax * SCALE);
            float fac = __expf(mr[nf] - newm);
            float ps = 0.f;
            unsigned pl[4], ph[4];
#pragma unroll
            for (int f = 0; f < 4; f++) {
                float p0 = __expf(fmaf(sp[f][nf][0], SCALE, -newm));
                float p1 = __expf(fmaf(sp[f][nf][1], SCALE, -newm));
                float p2 = __expf(fmaf(sp[f][nf][2], SCALE, -newm));
                float p3 = __expf(fmaf(sp[f][nf][3], SCALE, -newm));
                ps += (p0 + p1) + (p2 + p3);
                pl[f] = f2b(p0) | (f2b(p1) << 16);
                ph[f] = f2b(p2) | (f2b(p3) << 16);
            }
            ps += __shfl_xor(ps, 16);
            ps += __shfl_xor(ps, 32);
            lr[nf] = fmaf(lr[nf], fac, ps);
            mr[nf] = newm;
#pragma unroll
            for (int pt = 0; pt < 8; pt++)
#pragma unroll
                for (int r = 0; r < 4; r++) O[pt][nf][r] *= fac;
            // exchange: B reg r at lane(g') holds bf16 pair for m=32kc+8g'+2r,+2r+1
#pragma unroll
            for (int kc = 0; kc < 2; kc++) {
                unsigned a0 = (unsigned)__shfl((int)pl[2 * kc], srcA);
                unsigned a1 = (unsigned)__shfl((int)ph[2 * kc], srcA);
                unsigned b0 = (unsigned)__shfl((int)pl[2 * kc + 1], srcA);
                unsigned b1 = (unsigned)__shfl((int)ph[2 * kc + 1], srcA);
                unsigned a2 = (unsigned)__shfl((int)pl[2 * kc], srcB);
                unsigned a3 = (unsigned)__shfl((int)ph[2 * kc], srcB);
                unsigned b2 = (unsigned)__shfl((int)pl[2 * kc + 1], srcB);
                unsigned b3 = (unsigned)__shfl((int)ph[2 * kc + 1], srcB);
                Bp[nf][kc].u[0] = hi ? b0 : a0;
                Bp[nf][kc].u[1] = hi ? b1 : a1;
                Bp[nf][kc].u[2] = hi ? b2 : a2;
                Bp[nf][kc].u[3] = hi ? b3 : a3;
            }
        }
        // ---- PV: O += V @ P ----
#pragma unroll
        for (int pt = 0; pt < 8; pt++) {
#pragma unroll
            for (int kc = 0; kc < 2; kc++) {
                bf16x8 vf = *(const bf16x8*)(vb + (((size_t)(pt * 16 + l15)) << 10) + m0 + kc * 32 + g * 8);
                O[pt][0] = MFMA16(vf, Bp[0][kc].v, O[pt][0]);
                O[pt][1] = MFMA16(vf, Bp[1][kc].v, O[pt][1]);
            }
        }
    }
    // ---- epilogue ----
    float inv0 = 1.f / lr[0], inv1 = 1.f / lr[1];
#pragma unroll
    for (int pt = 0; pt < 8; pt++) {
#pragma unroll
        for (int r = 0; r < 4; r++) {
            int prow = pt * 16 + 4 * g + r;
            size_t base = (((size_t)(b * 128 + prow)) << 12) + n0 + l15;
            a_out[base] = O[pt][0][r] * inv0;
            a_out[base + 16] = O[pt][1][r] * inv1;
        }
    }
}

// ---------------- cat(relu) 1x1 conv + residual -> x1 (into out) ----------------
__global__ __launch_bounds__(256) void catconv_kernel(const float* __restrict__ a_in, const float* __restrict__ t,
                                                      const float* __restrict__ x, const float* __restrict__ w_out,
                                                      const float* __restrict__ s_out, const float* __restrict__ b_out,
                                                      float* __restrict__ out) {
    int pxt = blockIdx.x, cot = blockIdx.y, b = blockIdx.z;
    int tid = threadIdx.x;
    __shared__ float Xs[16 * 64];
    __shared__ float Ws[64 * 17];
    int tc = tid & 15, tr = tid >> 4;
    float acc[4][4];
#pragma unroll
    for (int o = 0; o < 4; o++)
#pragma unroll
        for (int j = 0; j < 4; j++) acc[o][j] = 0.f;
    int px0 = pxt * 64, co0 = cot * 64;
    for (int ch = 0; ch < 16; ch++) {
        __syncthreads();
        int ci0 = ch * 16;
        int i = tid;
#pragma unroll
        for (int rep = 0; rep < 4; rep++, i += 256) {
            int cic = i >> 6, pxl = i & 63;
            int ci = ci0 + cic;
            float val = (ci < 128) ? a_in[(((size_t)b * 128 + ci) << 12) + px0 + pxl]
                                   : t[(((size_t)b * 384 + 128 + ci) << 12) + px0 + pxl];
            Xs[cic * 64 + pxl] = fmaxf(val, 0.f);
        }
        i = tid;
#pragma unroll
        for (int rep = 0; rep < 4; rep++, i += 256) {
            int cor = i >> 4, cic = i & 15;
            Ws[cor * 17 + cic] = w_out[(size_t)(co0 + cor) * 256 + ci0 + cic];
        }
        __syncthreads();
#pragma unroll
        for (int cic = 0; cic < 16; cic++) {
            float av[4], bv[4];
#pragma unroll
            for (int o = 0; o < 4; o++) av[o] = Ws[(tr * 4 + o) * 17 + cic];
#pragma unroll
            for (int j = 0; j < 4; j++) bv[j] = Xs[cic * 64 + tc * 4 + j];
#pragma unroll
            for (int o = 0; o < 4; o++)
#pragma unroll
                for (int j = 0; j < 4; j++) acc[o][j] = fmaf(av[o], bv[j], acc[o][j]);
        }
    }
#pragma unroll
    for (int o = 0; o < 4; o++) {
        int co = co0 + tr * 4 + o;
        float sc = s_out[co], bi = b_out[co];
        size_t base = (((size_t)b * 256 + co) << 12) + px0 + tc * 4;
#pragma unroll
        for (int j = 0; j < 4; j++)
            out[base + j] = x[base + j] + fmaf(acc[o][j], sc, bi);
    }
}

// ---------------- FFN1: h = relu(bn(W1 @ x1)), bf16 out ----------------
__global__ __launch_bounds__(256) void ffn1_kernel(const float* __restrict__ x1, const float* __restrict__ w1,
                                                   const float* __restrict__ s1, const float* __restrict__ b1,
                                                   __hip_bfloat16* __restrict__ h) {
    int pxt = blockIdx.x, cot = blockIdx.y, b = blockIdx.z;
    int tid = threadIdx.x;
    __shared__ float Xs[16 * 64];
    __shared__ float Ws[64 * 17];
    int tc = tid & 15, tr = tid >> 4;
    float acc[4][4];
#pragma unroll
    for (int o = 0; o < 4; o++)
#pragma unroll
        for (int j = 0; j < 4; j++) acc[o][j] = 0.f;
    int px0 = pxt * 64, co0 = cot * 64;
    for (int ch = 0; ch < 16; ch++) {
        __syncthreads();
        int ci0 = ch * 16;
        int i = tid;
#pragma unroll
        for (int rep = 0; rep < 4; rep++, i += 256) {
            int cic = i >> 6, pxl = i & 63;
            Xs[cic * 64 + pxl] = x1[(((size_t)b * 256 + ci0 + cic) << 12) + px0 + pxl];
        }
        i = tid;
#pragma unroll
        for (int rep = 0; rep < 4; rep++, i += 256) {
            int cor = i >> 4, cic = i & 15;
            Ws[cor * 17 + cic] = w1[(size_t)(co0 + cor) * 256 + ci0 + cic];
        }
        __syncthreads();
#pragma unroll
        for (int cic = 0; cic < 16; cic++) {
            float av[4], bv[4];
#pragma unroll
            for (int o = 0; o < 4; o++) av[o] = Ws[(tr * 4 + o) * 17 + cic];
#pragma unroll
            for (int j = 0; j < 4; j++) bv[j] = Xs[cic * 64 + tc * 4 + j];
#pragma unroll
            for (int o = 0; o < 4; o++)
#pragma unroll
                for (int j = 0; j < 4; j++) acc[o][j] = fmaf(av[o], bv[j], acc[o][j]);
        }
    }
#pragma unroll
    for (int o = 0; o < 4; o++) {
        int hc = co0 + tr * 4 + o;
        float sc = s1[hc], bi = b1[hc];
        size_t base = (((size_t)b * 512 + hc) << 12) + px0 + tc * 4;
#pragma unroll
        for (int j = 0; j < 4; j++)
            h[base + j] = __float2bfloat16(fmaxf(fmaf(acc[o][j], sc, bi), 0.f));
    }
}

// ---------------- FFN2: out = x1 + bn(W2 @ h) ----------------
__global__ __launch_bounds__(256) void ffn2_kernel(const __hip_bfloat16* __restrict__ h, const float* __restrict__ w2,
                                                   const float* __restrict__ s2, const float* __restrict__ b2,
                                                   float* __restrict__ out) {
    int pxt = blockIdx.x, cot = blockIdx.y, b = blockIdx.z;
    int tid = threadIdx.x;
    __shared__ float Xs[16 * 64];
    __shared__ float Ws[64 * 17];
    int tc = tid & 15, tr = tid >> 4;
    float acc[4][4];
#pragma unroll
    for (int o = 0; o < 4; o++)
#pragma unroll
        for (int j = 0; j < 4; j++) acc[o][j] = 0.f;
    int px0 = pxt * 64, co0 = cot * 64;
    for (int ch = 0; ch < 32; ch++) {
        __syncthreads();
        int ci0 = ch * 16;
        int i = tid;
#pragma unroll
        for (int rep = 0; rep < 4; rep++, i += 256) {
            int cic = i >> 6, pxl = i & 63;
            Xs[cic * 64 + pxl] = __bfloat162float(h[(((size_t)b * 512 + ci0 + cic) << 12) + px0 + pxl]);
        }
        i = tid;
#pragma unroll
        for (int rep = 0; rep < 4; rep++, i += 256) {
            int cor = i >> 4, cic = i & 15;
            Ws[cor * 17 + cic] = w2[(size_t)(co0 + cor) * 512 + ci0 + cic];
        }
        __syncthreads();
#pragma unroll
        for (int cic = 0; cic < 16; cic++) {
            float av[4], bv[4];
#pragma unroll
            for (int o = 0; o < 4; o++) av[o] = Ws[(tr * 4 + o) * 17 + cic];
#pragma unroll
            for (int j = 0; j < 4; j++) bv[j] = Xs[cic * 64 + tc * 4 + j];
#pragma unroll
            for (int o = 0; o < 4; o++)
#pragma unroll
                for (int j = 0; j < 4; j++) acc[o][j] = fmaf(av[o], bv[j], acc[o][j]);
        }
    }
#pragma unroll
    for (int o = 0; o < 4; o++) {
        int co = co0 + tr * 4 + o;
        float sc = s2[co], bi = b2[co];
        size_t base = (((size_t)b * 256 + co) << 12) + px0 + tc * 4;
#pragma unroll
        for (int j = 0; j < 4; j++)
            out[base + j] = out[base + j] + fmaf(acc[o][j], sc, bi);
    }
}

extern "C" void kernel_launch(void* const* d_in, const int* in_sizes, int n_in,
                              void* d_out, int out_size, void* d_ws, size_t ws_size,
                              hipStream_t stream) {
    const float* x    = (const float*)d_in[0];
    const float* gn_w = (const float*)d_in[1];
    const float* gn_b = (const float*)d_in[2];
    const float* w_in = (const float*)d_in[3];
    const float* s_in = (const float*)d_in[4];
    const float* b_in = (const float*)d_in[5];
    const float* w_k  = (const float*)d_in[6];
    const float* s_k  = (const float*)d_in[7];
    const float* b_k  = (const float*)d_in[8];
    const float* w_v  = (const float*)d_in[9];
    const float* s_v  = (const float*)d_in[10];
    const float* b_v  = (const float*)d_in[11];
    const float* w_out= (const float*)d_in[12];
    const float* s_out= (const float*)d_in[13];
    const float* b_out= (const float*)d_in[14];
    const float* w1   = (const float*)d_in[15];
    const float* s1   = (const float*)d_in[16];
    const float* b1   = (const float*)d_in[17];
    const float* w2   = (const float*)d_in[18];
    const float* s2   = (const float*)d_in[19];
    const float* b2   = (const float*)d_in[20];
    float* out = (float*)d_out;
    float* ws = (float*)d_ws;

    float* part = ws;                          // 2048 floats
    float* Aarr = ws + 2048;                   // 4096
    float* Barr = ws + 6144;                   // 4096
    float* t    = ws + 10240;                  // 16*384*4096 = 25165824 floats
    float* a    = t + 25165824;                // 16*128*4096 = 8388608 floats (ends 33564672)
    __hip_bfloat16* h = (__hip_bfloat16*)(ws + 33564672);   // 16*512*4096 bf16 (16777216 floats)
    // q_t aliases h: q_t dead before ffn1 writes h (stream-ordered)
    unsigned short* q_t  = (unsigned short*)(ws + 33564672); // 16*4096*64 bf16
    unsigned short* kd_t = (unsigned short*)(ws + 50341888); // 16*1024*64 bf16 (524288 floats)
    unsigned short* vd_b = (unsigned short*)(ws + 50866176); // 16*128*1024 bf16 (1048576 floats)

    gn_part_kernel<<<dim3(64, 16), 256, 0, stream>>>(x, part);
    gn_final_kernel<<<16, 256, 0, stream>>>(part, gn_w, gn_b, Aarr, Barr);
    conv3_kernel<<<dim3(12, 16, 16), 256, 0, stream>>>(x, Aarr, Barr, w_in, s_in, b_in, t);
    dw_kernel<<<12288, 256, 0, stream>>>(t, w_k, s_k, b_k, w_v, s_v, b_v, kd_t, vd_b);
    qt_kernel<<<dim3(64, 16), 256, 0, stream>>>(t, q_t);
    attn_mfma_kernel<<<dim3(32, 16), 256, 0, stream>>>(q_t, kd_t, vd_b, a);
    catconv_kernel<<<dim3(64, 4, 16), 256, 0, stream>>>(a, t, x, w_out, s_out, b_out, out);
    ffn1_kernel<<<dim3(64, 8, 16), 256, 0, stream>>>(out, w1, s1, b1, h);
    ffn2_kernel<<<dim3(64, 4, 16), 256, 0, stream>>>(h, w2, s2, b2, out);
}

// Round 3
// 1124.921 us; speedup vs baseline: 3.8394x; 2.1831x over previous
//
#include <hip/hip_runtime.h>
#include <hip/hip_bf16.h>

#define DIM 256
#define QK 64
#define PD 128
#define HID 512
#define NPX 4096          // 64*64 pixels per image
#define NB 16
#define SCALE 0.125f      // 64^-0.5
#define GN_EPS 1e-5f

typedef short bf16x8 __attribute__((ext_vector_type(8)));
typedef float f32x4 __attribute__((ext_vector_type(4)));
#define MFMA16(a, b, c) __builtin_amdgcn_mfma_f32_16x16x32_bf16(a, b, c, 0, 0, 0)

__device__ __forceinline__ unsigned f2b(float f) {
    unsigned u = __float_as_uint(f);
    return (u + 0x7fffu + ((u >> 16) & 1u)) >> 16;  // RNE bf16, as low 16 bits
}

// ---------------- GroupNorm stats ----------------
__global__ __launch_bounds__(256) void gn_part_kernel(const float* __restrict__ x, float* __restrict__ part) {
    int chunk = blockIdx.x, b = blockIdx.y;
    const float* xp = x + (size_t)b * (DIM * NPX) + (size_t)chunk * 16384;
    float s = 0.f, ss = 0.f;
    for (int i = threadIdx.x; i < 16384; i += 256) { float v = xp[i]; s += v; ss += v * v; }
    for (int off = 32; off > 0; off >>= 1) { s += __shfl_down(s, off); ss += __shfl_down(ss, off); }
    __shared__ float red[8];
    int w = threadIdx.x >> 6;
    if ((threadIdx.x & 63) == 0) { red[w * 2] = s; red[w * 2 + 1] = ss; }
    __syncthreads();
    if (threadIdx.x == 0) {
        float S = red[0] + red[2] + red[4] + red[6];
        float SS = red[1] + red[3] + red[5] + red[7];
        part[(b * 64 + chunk) * 2] = S;
        part[(b * 64 + chunk) * 2 + 1] = SS;
    }
}

__global__ __launch_bounds__(256) void gn_final_kernel(const float* __restrict__ part,
                                                       const float* __restrict__ gn_w, const float* __restrict__ gn_b,
                                                       float* __restrict__ Aarr, float* __restrict__ Barr) {
    int b = blockIdx.x;
    float s = 0.f, ss = 0.f;
    if (threadIdx.x < 64) {
        s = part[(b * 64 + threadIdx.x) * 2];
        ss = part[(b * 64 + threadIdx.x) * 2 + 1];
        for (int off = 32; off > 0; off >>= 1) { s += __shfl_down(s, off); ss += __shfl_down(ss, off); }
    }
    __shared__ float sh[2];
    if (threadIdx.x == 0) {
        const float invN = 1.f / (float)(DIM * NPX);
        float mu = s * invN;
        float var = ss * invN - mu * mu;
        sh[0] = mu; sh[1] = rsqrtf(var + GN_EPS);
    }
    __syncthreads();
    float mu = sh[0], rstd = sh[1];
    int c = threadIdx.x;
    float g = gn_w[c] * rstd;
    Aarr[b * 256 + c] = g;
    Barr[b * 256 + c] = gn_b[c] - mu * g;
}

// ---------------- xn -> bf16 channels-last [B][64][64][256] ----------------
__global__ __launch_bounds__(256) void xnb_kernel(const float* __restrict__ x,
                                                  const float* __restrict__ Aarr, const float* __restrict__ Barr,
                                                  unsigned short* __restrict__ xb) {
    int y = blockIdx.x, b = blockIdx.y;
    int tid = threadIdx.x;
    __shared__ unsigned short tile[64 * 264];  // [px][ci], stride 264
    const float* xr = x + ((size_t)b << 20) + (size_t)y * 64;
    const float* Ab = Aarr + b * 256;
    const float* Bb = Barr + b * 256;
    for (int it = 0; it < 64; it++) {
        int lin = it * 256 + tid;
        int c = lin >> 6, px = lin & 63;
        float v = fmaf(xr[((size_t)c << 12) + px], Ab[c], Bb[c]);
        tile[px * 264 + c] = (unsigned short)f2b(v);
    }
    __syncthreads();
    unsigned short* ob = xb + (((size_t)(b * 64 + y)) << 14);  // *64*256
    for (int it = 0; it < 8; it++) {
        int lin = it * 256 + tid;
        int px = lin >> 5, g = lin & 31;
        *(uint4*)&ob[px * 256 + g * 8] = *(const uint4*)&tile[px * 264 + g * 8];
    }
}

// ---------------- weights -> bf16 [oc][tap][ci] ----------------
__global__ __launch_bounds__(256) void wb_kernel(const float* __restrict__ w_in, unsigned short* __restrict__ wb) {
    int idx = blockIdx.x * 256 + threadIdx.x;  // 384*9*256
    if (idx < 884736) {
        int ci = idx & 255;
        int tap = (idx >> 8) % 9;
        int oc = idx / 2304;
        wb[idx] = (unsigned short)f2b(w_in[(size_t)(oc * 256 + ci) * 9 + tap]);
    }
}

// ---------------- conv3x3 implicit-GEMM MFMA ----------------
// block: 4 waves, tile 96 oc x (4 rows x 64 px); wave w -> image row y0+w.
// K = 8 ci-chunks of 32 x 9 taps. xs halo tile [6 rows][66 cols][40 pad] bf16.
__global__ __launch_bounds__(256) void conv3_mfma_kernel(const unsigned short* __restrict__ xb,
                                                         const unsigned short* __restrict__ wb,
                                                         const float* __restrict__ s_in, const float* __restrict__ b_in,
                                                         float* __restrict__ t) {
    int ocb = blockIdx.x, rg = blockIdx.y, b = blockIdx.z;
    int tid = threadIdx.x;
    int w = tid >> 6, lane = tid & 63, g = lane >> 4, l15 = lane & 15;
    __shared__ unsigned short xs[6 * 66 * 40];
    int oc0 = ocb * 96, y0 = rg * 4;
    f32x4 acc[6][4];
#pragma unroll
    for (int o = 0; o < 6; o++)
#pragma unroll
        for (int p = 0; p < 4; p++)
#pragma unroll
            for (int r = 0; r < 4; r++) acc[o][p][r] = 0.f;
    // zero the 2 halo columns (slots 0 and 65), first 32 ci slots
    if (tid < 48) {
        int row = tid >> 3, cp = (tid >> 2) & 1, gg = tid & 3;
        int col = cp ? 65 : 0;
        *(uint4*)&xs[(row * 66 + col) * 40 + gg * 8] = make_uint4(0, 0, 0, 0);
    }
    const unsigned short* xg = xb + ((size_t)b << 20);  // [64][64][256]
    for (int ck = 0; ck < 8; ck++) {
        int ci0 = ck * 32;
        __syncthreads();
#pragma unroll
        for (int it = 0; it < 6; it++) {
            int lin = it * 256 + tid;
            int gg = lin & 3, col = (lin >> 2) & 63, row = lin >> 8;
            int y = y0 - 1 + row;
            uint4 val = make_uint4(0, 0, 0, 0);
            if (y >= 0 && y < 64)
                val = *(const uint4*)(xg + (((size_t)(y * 64 + col)) << 8) + ci0 + gg * 8);
            *(uint4*)&xs[(row * 66 + col + 1) * 40 + gg * 8] = val;
        }
        __syncthreads();
#pragma unroll
        for (int tap = 0; tap < 9; tap++) {
            int dy = tap / 3, dx = tap % 3;
            bf16x8 Af[6], Bf[4];
#pragma unroll
            for (int o = 0; o < 6; o++)
                Af[o] = *(const bf16x8*)(wb + ((size_t)(oc0 + o * 16 + l15) * 9 + tap) * 256 + ci0 + g * 8);
#pragma unroll
            for (int p = 0; p < 4; p++)
                Bf[p] = *(const bf16x8*)&xs[((w + dy) * 66 + p * 16 + l15 + dx) * 40 + g * 8];
#pragma unroll
            for (int o = 0; o < 6; o++)
#pragma unroll
                for (int p = 0; p < 4; p++)
                    acc[o][p] = MFMA16(Af[o], Bf[p], acc[o][p]);
        }
    }
    int y = y0 + w;
#pragma unroll
    for (int o = 0; o < 6; o++) {
        int ocb4 = oc0 + o * 16 + 4 * g;
#pragma unroll
        for (int r = 0; r < 4; r++) {
            int oc = ocb4 + r;
            float sc = s_in[oc], bi = b_in[oc];
            size_t base = (((size_t)b * 384 + oc) << 12) + (size_t)y * 64 + l15;
#pragma unroll
            for (int p = 0; p < 4; p++)
                t[base + p * 16] = fmaf(acc[o][p][r], sc, bi);
        }
    }
}

// ---------------- depthwise 2x2 stride-2 for k and v (bf16 outputs for MFMA attn) ----------------
// kd_t: [B][1024 m][64 c] bf16 ; vd_b: [B][128 p][1024 m] bf16
__global__ __launch_bounds__(256) void dw_kernel(const float* __restrict__ t,
                                                 const float* __restrict__ w_k, const float* __restrict__ s_k, const float* __restrict__ b_k,
                                                 const float* __restrict__ w_v, const float* __restrict__ s_v, const float* __restrict__ b_v,
                                                 unsigned short* __restrict__ kd_t, unsigned short* __restrict__ vd_b) {
    int gid = blockIdx.x * 256 + threadIdx.x;
    if (gid < (1 << 20)) {
        int b = gid >> 16, c = (gid >> 10) & 63, m = gid & 1023;
        int yo = m >> 5, xo = m & 31;
        const float* src = t + (((size_t)b * 384 + 64 + c) << 12) + (size_t)(yo * 2) * 64 + xo * 2;
        float v = w_k[c * 4] * src[0] + w_k[c * 4 + 1] * src[1] + w_k[c * 4 + 2] * src[64] + w_k[c * 4 + 3] * src[65];
        kd_t[((size_t)(b * 1024 + m) << 6) + c] = (unsigned short)f2b(fmaf(v, s_k[c], b_k[c]));
    } else {
        int gg = gid - (1 << 20);
        int b = gg >> 17, c = (gg >> 10) & 127, m = gg & 1023;
        int yo = m >> 5, xo = m & 31;
        const float* src = t + (((size_t)b * 384 + 128 + c) << 12) + (size_t)(yo * 2) * 64 + xo * 2;
        float v = w_v[c * 4] * src[0] + w_v[c * 4 + 1] * src[1] + w_v[c * 4 + 2] * src[64] + w_v[c * 4 + 3] * src[65];
        vd_b[gg] = (unsigned short)f2b(fmaf(v, s_v[c], b_v[c]));
    }
}

// ---------------- q transpose: t ch 0..63 [c][n] -> q_t [n][c] bf16 ----------------
__global__ __launch_bounds__(256) void qt_kernel(const float* __restrict__ t, unsigned short* __restrict__ q_t) {
    int nt = blockIdx.x, b = blockIdx.y;
    int tid = threadIdx.x;
    __shared__ float tile[64][65];
    const float* tb = t + (((size_t)b * 384) << 12) + nt * 64;
    for (int i = tid; i < 4096; i += 256) {
        int c = i >> 6, nl = i & 63;
        tile[c][nl] = tb[((size_t)c << 12) + nl];
    }
    __syncthreads();
    unsigned short* qb = q_t + (((size_t)b * 4096 + nt * 64) << 6);
    for (int i = tid; i < 4096; i += 256) {
        int n = i >> 6, c = i & 63;
        qb[((size_t)n << 6) + c] = (unsigned short)f2b(tile[c][n]);
    }
}

// ---------------- MFMA flash attention ----------------
__global__ __launch_bounds__(256) void attn_mfma_kernel(const unsigned short* __restrict__ q_t,
                                                        const unsigned short* __restrict__ kd_t,
                                                        const unsigned short* __restrict__ vd_b,
                                                        float* __restrict__ a_out) {
    int tid = threadIdx.x;
    int wid = tid >> 6, lane = tid & 63;
    int g = lane >> 4, l15 = lane & 15;
    int b = blockIdx.y;
    int n0 = (blockIdx.x * 4 + wid) * 32;

    bf16x8 qf[2][2];
#pragma unroll
    for (int nf = 0; nf < 2; nf++)
#pragma unroll
        for (int kc = 0; kc < 2; kc++)
            qf[nf][kc] = *(const bf16x8*)(q_t + (((size_t)b * 4096 + n0 + 16 * nf + l15) << 6) + kc * 32 + g * 8);

    f32x4 O[8][2];
#pragma unroll
    for (int pt = 0; pt < 8; pt++)
#pragma unroll
        for (int nf = 0; nf < 2; nf++)
#pragma unroll
            for (int r = 0; r < 4; r++) O[pt][nf][r] = 0.f;
    float mr[2] = {-1e30f, -1e30f}, lr[2] = {0.f, 0.f};

    const unsigned short* kb = kd_t + ((size_t)b << 16);         // [1024][64]
    const unsigned short* vb = vd_b + ((size_t)(b * 128) << 10); // [128][1024]

    union BU { unsigned u[4]; bf16x8 v; };

    for (int mt = 0; mt < 16; mt++) {
        int m0 = mt * 64;
        f32x4 sp[4][2];
#pragma unroll
        for (int f = 0; f < 4; f++)
#pragma unroll
            for (int nf = 0; nf < 2; nf++)
#pragma unroll
                for (int r = 0; r < 4; r++) sp[f][nf][r] = 0.f;
#pragma unroll
        for (int f = 0; f < 4; f++) {
#pragma unroll
            for (int kc = 0; kc < 2; kc++) {
                bf16x8 kf = *(const bf16x8*)(kb + (((size_t)(m0 + 16 * f + l15)) << 6) + kc * 32 + g * 8);
                sp[f][0] = MFMA16(kf, qf[0][kc], sp[f][0]);
                sp[f][1] = MFMA16(kf, qf[1][kc], sp[f][1]);
            }
        }
        BU Bp[2][2];
        int srcA = l15 + ((g & 1) << 5);
        int srcB = srcA + 16;
        bool hi = (g >> 1) != 0;
#pragma unroll
        for (int nf = 0; nf < 2; nf++) {
            float tmax = -1e30f;
#pragma unroll
            for (int f = 0; f < 4; f++)
#pragma unroll
                for (int r = 0; r < 4; r++) tmax = fmaxf(tmax, sp[f][nf][r]);
            tmax = fmaxf(tmax, __shfl_xor(tmax, 16));
            tmax = fmaxf(tmax, __shfl_xor(tmax, 32));
            float newm = fmaxf(mr[nf], tmax * SCALE);
            float fac = __expf(mr[nf] - newm);
            float ps = 0.f;
            unsigned pl[4], ph[4];
#pragma unroll
            for (int f = 0; f < 4; f++) {
                float p0 = __expf(fmaf(sp[f][nf][0], SCALE, -newm));
                float p1 = __expf(fmaf(sp[f][nf][1], SCALE, -newm));
                float p2 = __expf(fmaf(sp[f][nf][2], SCALE, -newm));
                float p3 = __expf(fmaf(sp[f][nf][3], SCALE, -newm));
                ps += (p0 + p1) + (p2 + p3);
                pl[f] = f2b(p0) | (f2b(p1) << 16);
                ph[f] = f2b(p2) | (f2b(p3) << 16);
            }
            ps += __shfl_xor(ps, 16);
            ps += __shfl_xor(ps, 32);
            lr[nf] = fmaf(lr[nf], fac, ps);
            mr[nf] = newm;
#pragma unroll
            for (int pt = 0; pt < 8; pt++)
#pragma unroll
                for (int r = 0; r < 4; r++) O[pt][nf][r] *= fac;
#pragma unroll
            for (int kc = 0; kc < 2; kc++) {
                unsigned a0 = (unsigned)__shfl((int)pl[2 * kc], srcA);
                unsigned a1 = (unsigned)__shfl((int)ph[2 * kc], srcA);
                unsigned b0 = (unsigned)__shfl((int)pl[2 * kc + 1], srcA);
                unsigned b1 = (unsigned)__shfl((int)ph[2 * kc + 1], srcA);
                unsigned a2 = (unsigned)__shfl((int)pl[2 * kc], srcB);
                unsigned a3 = (unsigned)__shfl((int)ph[2 * kc], srcB);
                unsigned b2 = (unsigned)__shfl((int)pl[2 * kc + 1], srcB);
                unsigned b3 = (unsigned)__shfl((int)ph[2 * kc + 1], srcB);
                Bp[nf][kc].u[0] = hi ? b0 : a0;
                Bp[nf][kc].u[1] = hi ? b1 : a1;
                Bp[nf][kc].u[2] = hi ? b2 : a2;
                Bp[nf][kc].u[3] = hi ? b3 : a3;
            }
        }
#pragma unroll
        for (int pt = 0; pt < 8; pt++) {
#pragma unroll
            for (int kc = 0; kc < 2; kc++) {
                bf16x8 vf = *(const bf16x8*)(vb + (((size_t)(pt * 16 + l15)) << 10) + m0 + kc * 32 + g * 8);
                O[pt][0] = MFMA16(vf, Bp[0][kc].v, O[pt][0]);
                O[pt][1] = MFMA16(vf, Bp[1][kc].v, O[pt][1]);
            }
        }
    }
    float inv0 = 1.f / lr[0], inv1 = 1.f / lr[1];
#pragma unroll
    for (int pt = 0; pt < 8; pt++) {
#pragma unroll
        for (int r = 0; r < 4; r++) {
            int prow = pt * 16 + 4 * g + r;
            size_t base = (((size_t)(b * 128 + prow)) << 12) + n0 + l15;
            a_out[base] = O[pt][0][r] * inv0;
            a_out[base + 16] = O[pt][1][r] * inv1;
        }
    }
}

// ---------------- cat(relu) 1x1 conv + residual -> x1 (into out) ----------------
__global__ __launch_bounds__(256) void catconv_kernel(const float* __restrict__ a_in, const float* __restrict__ t,
                                                      const float* __restrict__ x, const float* __restrict__ w_out,
                                                      const float* __restrict__ s_out, const float* __restrict__ b_out,
                                                      float* __restrict__ out) {
    int pxt = blockIdx.x, cot = blockIdx.y, b = blockIdx.z;
    int tid = threadIdx.x;
    __shared__ float Xs[16 * 64];
    __shared__ float Ws[64 * 17];
    int tc = tid & 15, tr = tid >> 4;
    float acc[4][4];
#pragma unroll
    for (int o = 0; o < 4; o++)
#pragma unroll
        for (int j = 0; j < 4; j++) acc[o][j] = 0.f;
    int px0 = pxt * 64, co0 = cot * 64;
    for (int ch = 0; ch < 16; ch++) {
        __syncthreads();
        int ci0 = ch * 16;
        int i = tid;
#pragma unroll
        for (int rep = 0; rep < 4; rep++, i += 256) {
            int cic = i >> 6, pxl = i & 63;
            int ci = ci0 + cic;
            float val = (ci < 128) ? a_in[(((size_t)b * 128 + ci) << 12) + px0 + pxl]
                                   : t[(((size_t)b * 384 + 128 + ci) << 12) + px0 + pxl];
            Xs[cic * 64 + pxl] = fmaxf(val, 0.f);
        }
        i = tid;
#pragma unroll
        for (int rep = 0; rep < 4; rep++, i += 256) {
            int cor = i >> 4, cic = i & 15;
            Ws[cor * 17 + cic] = w_out[(size_t)(co0 + cor) * 256 + ci0 + cic];
        }
        __syncthreads();
#pragma unroll
        for (int cic = 0; cic < 16; cic++) {
            float av[4], bv[4];
#pragma unroll
            for (int o = 0; o < 4; o++) av[o] = Ws[(tr * 4 + o) * 17 + cic];
#pragma unroll
            for (int j = 0; j < 4; j++) bv[j] = Xs[cic * 64 + tc * 4 + j];
#pragma unroll
            for (int o = 0; o < 4; o++)
#pragma unroll
                for (int j = 0; j < 4; j++) acc[o][j] = fmaf(av[o], bv[j], acc[o][j]);
        }
    }
#pragma unroll
    for (int o = 0; o < 4; o++) {
        int co = co0 + tr * 4 + o;
        float sc = s_out[co], bi = b_out[co];
        size_t base = (((size_t)b * 256 + co) << 12) + px0 + tc * 4;
#pragma unroll
        for (int j = 0; j < 4; j++)
            out[base + j] = x[base + j] + fmaf(acc[o][j], sc, bi);
    }
}

// ---------------- FFN1: h = relu(bn(W1 @ x1)), bf16 out ----------------
__global__ __launch_bounds__(256) void ffn1_kernel(const float* __restrict__ x1, const float* __restrict__ w1,
                                                   const float* __restrict__ s1, const float* __restrict__ b1,
                                                   __hip_bfloat16* __restrict__ h) {
    int pxt = blockIdx.x, cot = blockIdx.y, b = blockIdx.z;
    int tid = threadIdx.x;
    __shared__ float Xs[16 * 64];
    __shared__ float Ws[64 * 17];
    int tc = tid & 15, tr = tid >> 4;
    float acc[4][4];
#pragma unroll
    for (int o = 0; o < 4; o++)
#pragma unroll
        for (int j = 0; j < 4; j++) acc[o][j] = 0.f;
    int px0 = pxt * 64, co0 = cot * 64;
    for (int ch = 0; ch < 16; ch++) {
        __syncthreads();
        int ci0 = ch * 16;
        int i = tid;
#pragma unroll
        for (int rep = 0; rep < 4; rep++, i += 256) {
            int cic = i >> 6, pxl = i & 63;
            Xs[cic * 64 + pxl] = x1[(((size_t)b * 256 + ci0 + cic) << 12) + px0 + pxl];
        }
        i = tid;
#pragma unroll
        for (int rep = 0; rep < 4; rep++, i += 256) {
            int cor = i >> 4, cic = i & 15;
            Ws[cor * 17 + cic] = w1[(size_t)(co0 + cor) * 256 + ci0 + cic];
        }
        __syncthreads();
#pragma unroll
        for (int cic = 0; cic < 16; cic++) {
            float av[4], bv[4];
#pragma unroll
            for (int o = 0; o < 4; o++) av[o] = Ws[(tr * 4 + o) * 17 + cic];
#pragma unroll
            for (int j = 0; j < 4; j++) bv[j] = Xs[cic * 64 + tc * 4 + j];
#pragma unroll
            for (int o = 0; o < 4; o++)
#pragma unroll
                for (int j = 0; j < 4; j++) acc[o][j] = fmaf(av[o], bv[j], acc[o][j]);
        }
    }
#pragma unroll
    for (int o = 0; o < 4; o++) {
        int hc = co0 + tr * 4 + o;
        float sc = s1[hc], bi = b1[hc];
        size_t base = (((size_t)b * 512 + hc) << 12) + px0 + tc * 4;
#pragma unroll
        for (int j = 0; j < 4; j++)
            h[base + j] = __float2bfloat16(fmaxf(fmaf(acc[o][j], sc, bi), 0.f));
    }
}

// ---------------- FFN2: out = x1 + bn(W2 @ h) ----------------
__global__ __launch_bounds__(256) void ffn2_kernel(const __hip_bfloat16* __restrict__ h, const float* __restrict__ w2,
                                                   const float* __restrict__ s2, const float* __restrict__ b2,
                                                   float* __restrict__ out) {
    int pxt = blockIdx.x, cot = blockIdx.y, b = blockIdx.z;
    int tid = threadIdx.x;
    __shared__ float Xs[16 * 64];
    __shared__ float Ws[64 * 17];
    int tc = tid & 15, tr = tid >> 4;
    float acc[4][4];
#pragma unroll
    for (int o = 0; o < 4; o++)
#pragma unroll
        for (int j = 0; j < 4; j++) acc[o][j] = 0.f;
    int px0 = pxt * 64, co0 = cot * 64;
    for (int ch = 0; ch < 32; ch++) {
        __syncthreads();
        int ci0 = ch * 16;
        int i = tid;
#pragma unroll
        for (int rep = 0; rep < 4; rep++, i += 256) {
            int cic = i >> 6, pxl = i & 63;
            Xs[cic * 64 + pxl] = __bfloat162float(h[(((size_t)b * 512 + ci0 + cic) << 12) + px0 + pxl]);
        }
        i = tid;
#pragma unroll
        for (int rep = 0; rep < 4; rep++, i += 256) {
            int cor = i >> 4, cic = i & 15;
            Ws[cor * 17 + cic] = w2[(size_t)(co0 + cor) * 512 + ci0 + cic];
        }
        __syncthreads();
#pragma unroll
        for (int cic = 0; cic < 16; cic++) {
            float av[4], bv[4];
#pragma unroll
            for (int o = 0; o < 4; o++) av[o] = Ws[(tr * 4 + o) * 17 + cic];
#pragma unroll
            for (int j = 0; j < 4; j++) bv[j] = Xs[cic * 64 + tc * 4 + j];
#pragma unroll
            for (int o = 0; o < 4; o++)
#pragma unroll
                for (int j = 0; j < 4; j++) acc[o][j] = fmaf(av[o], bv[j], acc[o][j]);
        }
    }
#pragma unroll
    for (int o = 0; o < 4; o++) {
        int co = co0 + tr * 4 + o;
        float sc = s2[co], bi = b2[co];
        size_t base = (((size_t)b * 256 + co) << 12) + px0 + tc * 4;
#pragma unroll
        for (int j = 0; j < 4; j++)
            out[base + j] = out[base + j] + fmaf(acc[o][j], sc, bi);
    }
}

extern "C" void kernel_launch(void* const* d_in, const int* in_sizes, int n_in,
                              void* d_out, int out_size, void* d_ws, size_t ws_size,
                              hipStream_t stream) {
    const float* x    = (const float*)d_in[0];
    const float* gn_w = (const float*)d_in[1];
    const float* gn_b = (const float*)d_in[2];
    const float* w_in = (const float*)d_in[3];
    const float* s_in = (const float*)d_in[4];
    const float* b_in = (const float*)d_in[5];
    const float* w_k  = (const float*)d_in[6];
    const float* s_k  = (const float*)d_in[7];
    const float* b_k  = (const float*)d_in[8];
    const float* w_v  = (const float*)d_in[9];
    const float* s_v  = (const float*)d_in[10];
    const float* b_v  = (const float*)d_in[11];
    const float* w_out= (const float*)d_in[12];
    const float* s_out= (const float*)d_in[13];
    const float* b_out= (const float*)d_in[14];
    const float* w1   = (const float*)d_in[15];
    const float* s1   = (const float*)d_in[16];
    const float* b1   = (const float*)d_in[17];
    const float* w2   = (const float*)d_in[18];
    const float* s2   = (const float*)d_in[19];
    const float* b2   = (const float*)d_in[20];
    float* out = (float*)d_out;
    float* ws = (float*)d_ws;

    float* part = ws;                          // 2048 floats
    float* Aarr = ws + 2048;                   // 4096
    float* Barr = ws + 6144;                   // 4096
    float* t    = ws + 10240;                  // 16*384*4096 = 25165824 floats
    float* a    = t + 25165824;                // 16*128*4096 = 8388608 floats (ends 33564672)
    __hip_bfloat16* h = (__hip_bfloat16*)(ws + 33564672);   // 16*512*4096 bf16 (16777216 floats)
    // aliases (stream-ordered lifetimes):
    unsigned short* xb   = (unsigned short*)a;               // dead before attn writes a
    unsigned short* q_t  = (unsigned short*)(ws + 33564672); // first 2097152 floats of h region
    unsigned short* wb   = (unsigned short*)(ws + 35661824); // next 221184 floats; dead before ffn1
    unsigned short* kd_t = (unsigned short*)(ws + 50341888); // 16*1024*64 bf16
    unsigned short* vd_b = (unsigned short*)(ws + 50866176); // 16*128*1024 bf16

    gn_part_kernel<<<dim3(64, 16), 256, 0, stream>>>(x, part);
    gn_final_kernel<<<16, 256, 0, stream>>>(part, gn_w, gn_b, Aarr, Barr);
    xnb_kernel<<<dim3(64, 16), 256, 0, stream>>>(x, Aarr, Barr, xb);
    wb_kernel<<<3456, 256, 0, stream>>>(w_in, wb);
    conv3_mfma_kernel<<<dim3(4, 16, 16), 256, 0, stream>>>(xb, wb, s_in, b_in, t);
    dw_kernel<<<12288, 256, 0, stream>>>(t, w_k, s_k, b_k, w_v, s_v, b_v, kd_t, vd_b);
    qt_kernel<<<dim3(64, 16), 256, 0, stream>>>(t, q_t);
    attn_mfma_kernel<<<dim3(32, 16), 256, 0, stream>>>(q_t, kd_t, vd_b, a);
    catconv_kernel<<<dim3(64, 4, 16), 256, 0, stream>>>(a, t, x, w_out, s_out, b_out, out);
    ffn1_kernel<<<dim3(64, 8, 16), 256, 0, stream>>>(out, w1, s1, b1, h);
    ffn2_kernel<<<dim3(64, 4, 16), 256, 0, stream>>>(h, w2, s2, b2, out);
}

// Round 4
// 1103.006 us; speedup vs baseline: 3.9157x; 1.0199x over previous
//
#include <hip/hip_runtime.h>
#include <hip/hip_bf16.h>

#define DIM 256
#define QK 64
#define PD 128
#define HID 512
#define NPX 4096          // 64*64 pixels per image
#define NB 16
#define SCALE 0.125f      // 64^-0.5
#define GN_EPS 1e-5f

typedef short bf16x8 __attribute__((ext_vector_type(8)));
typedef float f32x4 __attribute__((ext_vector_type(4)));
#define MFMA16(a, b, c) __builtin_amdgcn_mfma_f32_16x16x32_bf16(a, b, c, 0, 0, 0)

__device__ __forceinline__ unsigned f2b(float f) {
    unsigned u = __float_as_uint(f);
    return (u + 0x7fffu + ((u >> 16) & 1u)) >> 16;  // RNE bf16, as low 16 bits
}

// ---------------- GroupNorm stats ----------------
__global__ __launch_bounds__(256) void gn_part_kernel(const float* __restrict__ x, float* __restrict__ part) {
    int chunk = blockIdx.x, b = blockIdx.y;
    const float* xp = x + (size_t)b * (DIM * NPX) + (size_t)chunk * 16384;
    float s = 0.f, ss = 0.f;
    for (int i = threadIdx.x; i < 16384; i += 256) { float v = xp[i]; s += v; ss += v * v; }
    for (int off = 32; off > 0; off >>= 1) { s += __shfl_down(s, off); ss += __shfl_down(ss, off); }
    __shared__ float red[8];
    int w = threadIdx.x >> 6;
    if ((threadIdx.x & 63) == 0) { red[w * 2] = s; red[w * 2 + 1] = ss; }
    __syncthreads();
    if (threadIdx.x == 0) {
        float S = red[0] + red[2] + red[4] + red[6];
        float SS = red[1] + red[3] + red[5] + red[7];
        part[(b * 64 + chunk) * 2] = S;
        part[(b * 64 + chunk) * 2 + 1] = SS;
    }
}

__global__ __launch_bounds__(256) void gn_final_kernel(const float* __restrict__ part,
                                                       const float* __restrict__ gn_w, const float* __restrict__ gn_b,
                                                       float* __restrict__ Aarr, float* __restrict__ Barr) {
    int b = blockIdx.x;
    float s = 0.f, ss = 0.f;
    if (threadIdx.x < 64) {
        s = part[(b * 64 + threadIdx.x) * 2];
        ss = part[(b * 64 + threadIdx.x) * 2 + 1];
        for (int off = 32; off > 0; off >>= 1) { s += __shfl_down(s, off); ss += __shfl_down(ss, off); }
    }
    __shared__ float sh[2];
    if (threadIdx.x == 0) {
        const float invN = 1.f / (float)(DIM * NPX);
        float mu = s * invN;
        float var = ss * invN - mu * mu;
        sh[0] = mu; sh[1] = rsqrtf(var + GN_EPS);
    }
    __syncthreads();
    float mu = sh[0], rstd = sh[1];
    int c = threadIdx.x;
    float g = gn_w[c] * rstd;
    Aarr[b * 256 + c] = g;
    Barr[b * 256 + c] = gn_b[c] - mu * g;
}

// ---------------- xn -> bf16 channels-last [B][64][64][256] ----------------
__global__ __launch_bounds__(256) void xnb_kernel(const float* __restrict__ x,
                                                  const float* __restrict__ Aarr, const float* __restrict__ Barr,
                                                  unsigned short* __restrict__ xb) {
    int y = blockIdx.x, b = blockIdx.y;
    int tid = threadIdx.x;
    __shared__ unsigned short tile[64 * 264];  // [px][ci], stride 264
    const float* xr = x + ((size_t)b << 20) + (size_t)y * 64;
    const float* Ab = Aarr + b * 256;
    const float* Bb = Barr + b * 256;
    for (int it = 0; it < 64; it++) {
        int lin = it * 256 + tid;
        int c = lin >> 6, px = lin & 63;
        float v = fmaf(xr[((size_t)c << 12) + px], Ab[c], Bb[c]);
        tile[px * 264 + c] = (unsigned short)f2b(v);
    }
    __syncthreads();
    unsigned short* ob = xb + (((size_t)(b * 64 + y)) << 14);  // *64*256
    for (int it = 0; it < 8; it++) {
        int lin = it * 256 + tid;
        int px = lin >> 5, g = lin & 31;
        *(uint4*)&ob[px * 256 + g * 8] = *(const uint4*)&tile[px * 264 + g * 8];
    }
}

// ---------------- weights -> bf16: wb [oc][tap][ci]; wob/w1b/w2b [O][I] ----------------
__global__ __launch_bounds__(256) void wcvt_kernel(const float* __restrict__ w_in, const float* __restrict__ w_out,
                                                   const float* __restrict__ w1, const float* __restrict__ w2,
                                                   unsigned short* __restrict__ wb, unsigned short* __restrict__ wob,
                                                   unsigned short* __restrict__ w1b, unsigned short* __restrict__ w2b) {
    int idx = blockIdx.x * 256 + threadIdx.x;
    if (idx < 884736) {
        int ci = idx & 255;
        int tap = (idx >> 8) % 9;
        int oc = idx / 2304;
        wb[idx] = (unsigned short)f2b(w_in[(size_t)(oc * 256 + ci) * 9 + tap]);
    } else if (idx < 950272) {
        int j = idx - 884736;
        wob[j] = (unsigned short)f2b(w_out[j]);
    } else if (idx < 1081344) {
        int j = idx - 950272;
        w1b[j] = (unsigned short)f2b(w1[j]);
    } else if (idx < 1212416) {
        int j = idx - 1081344;
        w2b[j] = (unsigned short)f2b(w2[j]);
    }
}

// ---------------- conv3x3 implicit-GEMM MFMA ----------------
__global__ __launch_bounds__(256, 4) void conv3_mfma_kernel(const unsigned short* __restrict__ xb,
                                                            const unsigned short* __restrict__ wb,
                                                            const float* __restrict__ s_in, const float* __restrict__ b_in,
                                                            float* __restrict__ t) {
    int ocb = blockIdx.x, rg = blockIdx.y, b = blockIdx.z;
    int tid = threadIdx.x;
    int w = tid >> 6, lane = tid & 63, g = lane >> 4, l15 = lane & 15;
    __shared__ unsigned short xs[6 * 66 * 40];
    int oc0 = ocb * 96, y0 = rg * 4;
    f32x4 acc[6][4];
#pragma unroll
    for (int o = 0; o < 6; o++)
#pragma unroll
        for (int p = 0; p < 4; p++)
#pragma unroll
            for (int r = 0; r < 4; r++) acc[o][p][r] = 0.f;
    if (tid < 48) {
        int row = tid >> 3, cp = (tid >> 2) & 1, gg = tid & 3;
        int col = cp ? 65 : 0;
        *(uint4*)&xs[(row * 66 + col) * 40 + gg * 8] = make_uint4(0, 0, 0, 0);
    }
    const unsigned short* xg = xb + ((size_t)b << 20);  // [64][64][256]
    for (int ck = 0; ck < 8; ck++) {
        int ci0 = ck * 32;
        __syncthreads();
#pragma unroll
        for (int it = 0; it < 6; it++) {
            int lin = it * 256 + tid;
            int gg = lin & 3, col = (lin >> 2) & 63, row = lin >> 8;
            int y = y0 - 1 + row;
            uint4 val = make_uint4(0, 0, 0, 0);
            if (y >= 0 && y < 64)
                val = *(const uint4*)(xg + (((size_t)(y * 64 + col)) << 8) + ci0 + gg * 8);
            *(uint4*)&xs[(row * 66 + col + 1) * 40 + gg * 8] = val;
        }
        __syncthreads();
#pragma unroll
        for (int tap = 0; tap < 9; tap++) {
            int dy = tap / 3, dx = tap % 3;
            bf16x8 Af[6], Bf[4];
#pragma unroll
            for (int o = 0; o < 6; o++)
                Af[o] = *(const bf16x8*)(wb + ((size_t)(oc0 + o * 16 + l15) * 9 + tap) * 256 + ci0 + g * 8);
#pragma unroll
            for (int p = 0; p < 4; p++)
                Bf[p] = *(const bf16x8*)&xs[((w + dy) * 66 + p * 16 + l15 + dx) * 40 + g * 8];
#pragma unroll
            for (int o = 0; o < 6; o++)
#pragma unroll
                for (int p = 0; p < 4; p++)
                    acc[o][p] = MFMA16(Af[o], Bf[p], acc[o][p]);
        }
    }
    int y = y0 + w;
#pragma unroll
    for (int o = 0; o < 6; o++) {
        int ocb4 = oc0 + o * 16 + 4 * g;
#pragma unroll
        for (int r = 0; r < 4; r++) {
            int oc = ocb4 + r;
            float sc = s_in[oc], bi = b_in[oc];
            size_t base = (((size_t)b * 384 + oc) << 12) + (size_t)y * 64 + l15;
#pragma unroll
            for (int p = 0; p < 4; p++)
                t[base + p * 16] = fmaf(acc[o][p][r], sc, bi);
        }
    }
}

// ---------------- depthwise 2x2 stride-2 for k and v (bf16 outputs for MFMA attn) ----------------
__global__ __launch_bounds__(256) void dw_kernel(const float* __restrict__ t,
                                                 const float* __restrict__ w_k, const float* __restrict__ s_k, const float* __restrict__ b_k,
                                                 const float* __restrict__ w_v, const float* __restrict__ s_v, const float* __restrict__ b_v,
                                                 unsigned short* __restrict__ kd_t, unsigned short* __restrict__ vd_b) {
    int gid = blockIdx.x * 256 + threadIdx.x;
    if (gid < (1 << 20)) {
        int b = gid >> 16, c = (gid >> 10) & 63, m = gid & 1023;
        int yo = m >> 5, xo = m & 31;
        const float* src = t + (((size_t)b * 384 + 64 + c) << 12) + (size_t)(yo * 2) * 64 + xo * 2;
        float v = w_k[c * 4] * src[0] + w_k[c * 4 + 1] * src[1] + w_k[c * 4 + 2] * src[64] + w_k[c * 4 + 3] * src[65];
        kd_t[((size_t)(b * 1024 + m) << 6) + c] = (unsigned short)f2b(fmaf(v, s_k[c], b_k[c]));
    } else {
        int gg = gid - (1 << 20);
        int b = gg >> 17, c = (gg >> 10) & 127, m = gg & 1023;
        int yo = m >> 5, xo = m & 31;
        const float* src = t + (((size_t)b * 384 + 128 + c) << 12) + (size_t)(yo * 2) * 64 + xo * 2;
        float v = w_v[c * 4] * src[0] + w_v[c * 4 + 1] * src[1] + w_v[c * 4 + 2] * src[64] + w_v[c * 4 + 3] * src[65];
        vd_b[gg] = (unsigned short)f2b(fmaf(v, s_v[c], b_v[c]));
    }
}

// ---------------- q transpose: t ch 0..63 [c][n] -> q_t [n][c] bf16 ----------------
__global__ __launch_bounds__(256) void qt_kernel(const float* __restrict__ t, unsigned short* __restrict__ q_t) {
    int nt = blockIdx.x, b = blockIdx.y;
    int tid = threadIdx.x;
    __shared__ float tile[64][65];
    const float* tb = t + (((size_t)b * 384) << 12) + nt * 64;
    for (int i = tid; i < 4096; i += 256) {
        int c = i >> 6, nl = i & 63;
        tile[c][nl] = tb[((size_t)c << 12) + nl];
    }
    __syncthreads();
    unsigned short* qb = q_t + (((size_t)b * 4096 + nt * 64) << 6);
    for (int i = tid; i < 4096; i += 256) {
        int n = i >> 6, c = i & 63;
        qb[((size_t)n << 6) + c] = (unsigned short)f2b(tile[c][n]);
    }
}

// ---------------- MFMA flash attention ----------------
__global__ __launch_bounds__(256) void attn_mfma_kernel(const unsigned short* __restrict__ q_t,
                                                        const unsigned short* __restrict__ kd_t,
                                                        const unsigned short* __restrict__ vd_b,
                                                        float* __restrict__ a_out) {
    int tid = threadIdx.x;
    int wid = tid >> 6, lane = tid & 63;
    int g = lane >> 4, l15 = lane & 15;
    int b = blockIdx.y;
    int n0 = (blockIdx.x * 4 + wid) * 32;

    bf16x8 qf[2][2];
#pragma unroll
    for (int nf = 0; nf < 2; nf++)
#pragma unroll
        for (int kc = 0; kc < 2; kc++)
            qf[nf][kc] = *(const bf16x8*)(q_t + (((size_t)b * 4096 + n0 + 16 * nf + l15) << 6) + kc * 32 + g * 8);

    f32x4 O[8][2];
#pragma unroll
    for (int pt = 0; pt < 8; pt++)
#pragma unroll
        for (int nf = 0; nf < 2; nf++)
#pragma unroll
            for (int r = 0; r < 4; r++) O[pt][nf][r] = 0.f;
    float mr[2] = {-1e30f, -1e30f}, lr[2] = {0.f, 0.f};

    const unsigned short* kb = kd_t + ((size_t)b << 16);         // [1024][64]
    const unsigned short* vb = vd_b + ((size_t)(b * 128) << 10); // [128][1024]

    union BU { unsigned u[4]; bf16x8 v; };

    for (int mt = 0; mt < 16; mt++) {
        int m0 = mt * 64;
        f32x4 sp[4][2];
#pragma unroll
        for (int f = 0; f < 4; f++)
#pragma unroll
            for (int nf = 0; nf < 2; nf++)
#pragma unroll
                for (int r = 0; r < 4; r++) sp[f][nf][r] = 0.f;
#pragma unroll
        for (int f = 0; f < 4; f++) {
#pragma unroll
            for (int kc = 0; kc < 2; kc++) {
                bf16x8 kf = *(const bf16x8*)(kb + (((size_t)(m0 + 16 * f + l15)) << 6) + kc * 32 + g * 8);
                sp[f][0] = MFMA16(kf, qf[0][kc], sp[f][0]);
                sp[f][1] = MFMA16(kf, qf[1][kc], sp[f][1]);
            }
        }
        BU Bp[2][2];
        int srcA = l15 + ((g & 1) << 5);
        int srcB = srcA + 16;
        bool hi = (g >> 1) != 0;
#pragma unroll
        for (int nf = 0; nf < 2; nf++) {
            float tmax = -1e30f;
#pragma unroll
            for (int f = 0; f < 4; f++)
#pragma unroll
                for (int r = 0; r < 4; r++) tmax = fmaxf(tmax, sp[f][nf][r]);
            tmax = fmaxf(tmax, __shfl_xor(tmax, 16));
            tmax = fmaxf(tmax, __shfl_xor(tmax, 32));
            float newm = fmaxf(mr[nf], tmax * SCALE);
            float fac = __expf(mr[nf] - newm);
            float ps = 0.f;
            unsigned pl[4], ph[4];
#pragma unroll
            for (int f = 0; f < 4; f++) {
                float p0 = __expf(fmaf(sp[f][nf][0], SCALE, -newm));
                float p1 = __expf(fmaf(sp[f][nf][1], SCALE, -newm));
                float p2 = __expf(fmaf(sp[f][nf][2], SCALE, -newm));
                float p3 = __expf(fmaf(sp[f][nf][3], SCALE, -newm));
                ps += (p0 + p1) + (p2 + p3);
                pl[f] = f2b(p0) | (f2b(p1) << 16);
                ph[f] = f2b(p2) | (f2b(p3) << 16);
            }
            ps += __shfl_xor(ps, 16);
            ps += __shfl_xor(ps, 32);
            lr[nf] = fmaf(lr[nf], fac, ps);
            mr[nf] = newm;
#pragma unroll
            for (int pt = 0; pt < 8; pt++)
#pragma unroll
                for (int r = 0; r < 4; r++) O[pt][nf][r] *= fac;
#pragma unroll
            for (int kc = 0; kc < 2; kc++) {
                unsigned a0 = (unsigned)__shfl((int)pl[2 * kc], srcA);
                unsigned a1 = (unsigned)__shfl((int)ph[2 * kc], srcA);
                unsigned b0 = (unsigned)__shfl((int)pl[2 * kc + 1], srcA);
                unsigned b1 = (unsigned)__shfl((int)ph[2 * kc + 1], srcA);
                unsigned a2 = (unsigned)__shfl((int)pl[2 * kc], srcB);
                unsigned a3 = (unsigned)__shfl((int)ph[2 * kc], srcB);
                unsigned b2 = (unsigned)__shfl((int)pl[2 * kc + 1], srcB);
                unsigned b3 = (unsigned)__shfl((int)ph[2 * kc + 1], srcB);
                Bp[nf][kc].u[0] = hi ? b0 : a0;
                Bp[nf][kc].u[1] = hi ? b1 : a1;
                Bp[nf][kc].u[2] = hi ? b2 : a2;
                Bp[nf][kc].u[3] = hi ? b3 : a3;
            }
        }
#pragma unroll
        for (int pt = 0; pt < 8; pt++) {
#pragma unroll
            for (int kc = 0; kc < 2; kc++) {
                bf16x8 vf = *(const bf16x8*)(vb + (((size_t)(pt * 16 + l15)) << 10) + m0 + kc * 32 + g * 8);
                O[pt][0] = MFMA16(vf, Bp[0][kc].v, O[pt][0]);
                O[pt][1] = MFMA16(vf, Bp[1][kc].v, O[pt][1]);
            }
        }
    }
    float inv0 = 1.f / lr[0], inv1 = 1.f / lr[1];
#pragma unroll
    for (int pt = 0; pt < 8; pt++) {
#pragma unroll
        for (int r = 0; r < 4; r++) {
            int prow = pt * 16 + 4 * g + r;
            size_t base = (((size_t)(b * 128 + prow)) << 12) + n0 + l15;
            a_out[base] = O[pt][0][r] * inv0;
            a_out[base + 16] = O[pt][1][r] * inv1;
        }
    }
}

// ---------------- acl: relu(cat(a,u)) -> channels-last bf16 [B][4096][256] ----------------
__global__ __launch_bounds__(256) void acl_kernel(const float* __restrict__ a_in, const float* __restrict__ t,
                                                  unsigned short* __restrict__ aucl) {
    int ng = blockIdx.x, b = blockIdx.y;
    int tid = threadIdx.x;
    __shared__ unsigned short tile[64 * 264];
    int n0 = ng * 64;
    int nl = tid & 63, c4 = tid >> 6;
    for (int it = 0; it < 64; it++) {
        int ci = it * 4 + c4;
        float v = (ci < 128) ? a_in[(((size_t)b * 128 + ci) << 12) + n0 + nl]
                             : t[(((size_t)b * 384 + 128 + ci) << 12) + n0 + nl];
        tile[nl * 264 + ci] = (unsigned short)f2b(fmaxf(v, 0.f));
    }
    __syncthreads();
    unsigned short* ob = aucl + (((size_t)(b * 4096 + n0)) << 8);
    for (int it = 0; it < 8; it++) {
        int lin = it * 256 + tid;
        int n = lin >> 5, cg = lin & 31;
        *(uint4*)&ob[n * 256 + cg * 8] = *(const uint4*)&tile[n * 264 + cg * 8];
    }
}

// ---------------- x1 -> channels-last bf16 [B][4096][256] ----------------
__global__ __launch_bounds__(256) void x1t_kernel(const float* __restrict__ x1, unsigned short* __restrict__ x1cl) {
    int ng = blockIdx.x, b = blockIdx.y;
    int tid = threadIdx.x;
    __shared__ unsigned short tile[64 * 264];
    int n0 = ng * 64;
    int nl = tid & 63, c4 = tid >> 6;
    for (int it = 0; it < 64; it++) {
        int ci = it * 4 + c4;
        float v = x1[(((size_t)b * 256 + ci) << 12) + n0 + nl];
        tile[nl * 264 + ci] = (unsigned short)f2b(v);
    }
    __syncthreads();
    unsigned short* ob = x1cl + (((size_t)(b * 4096 + n0)) << 8);
    for (int it = 0; it < 8; it++) {
        int lin = it * 256 + tid;
        int n = lin >> 5, cg = lin & 31;
        *(uint4*)&ob[n * 256 + cg * 8] = *(const uint4*)&tile[n * 264 + cg * 8];
    }
}

// ---------------- catconv MFMA: out = x + bn(W_out @ relu(cat)) ----------------
// A = wob[co][ci], B = aucl[px][ci]; D[co][px]. 4 waves over px (256 px/block).
__global__ __launch_bounds__(256) void catconv_mfma_kernel(const unsigned short* __restrict__ aucl,
                                                           const unsigned short* __restrict__ wob,
                                                           const float* __restrict__ x,
                                                           const float* __restrict__ s_out, const float* __restrict__ b_out,
                                                           float* __restrict__ out) {
    int tid = threadIdx.x;
    int w = tid >> 6, lane = tid & 63, g = lane >> 4, l15 = lane & 15;
    int b = blockIdx.z;
    int px0 = blockIdx.x * 256 + w * 64;
    int co0 = blockIdx.y * 64;
    f32x4 acc[4][4];
#pragma unroll
    for (int o = 0; o < 4; o++)
#pragma unroll
        for (int p = 0; p < 4; p++)
#pragma unroll
            for (int r = 0; r < 4; r++) acc[o][p][r] = 0.f;
    const unsigned short* ab = aucl + (((size_t)b * 4096) << 8);
    for (int kc = 0; kc < 8; kc++) {
        bf16x8 Af[4], Bf[4];
#pragma unroll
        for (int o = 0; o < 4; o++)
            Af[o] = *(const bf16x8*)(wob + (size_t)(co0 + o * 16 + l15) * 256 + kc * 32 + g * 8);
#pragma unroll
        for (int p = 0; p < 4; p++)
            Bf[p] = *(const bf16x8*)(ab + ((size_t)(px0 + p * 16 + l15) << 8) + kc * 32 + g * 8);
#pragma unroll
        for (int o = 0; o < 4; o++)
#pragma unroll
            for (int p = 0; p < 4; p++)
                acc[o][p] = MFMA16(Af[o], Bf[p], acc[o][p]);
    }
#pragma unroll
    for (int o = 0; o < 4; o++) {
#pragma unroll
        for (int r = 0; r < 4; r++) {
            int co = co0 + o * 16 + 4 * g + r;
            float sc = s_out[co], bi = b_out[co];
            size_t base = (((size_t)b * 256 + co) << 12) + px0 + l15;
#pragma unroll
            for (int p = 0; p < 4; p++)
                out[base + p * 16] = x[base + p * 16] + fmaf(acc[o][p][r], sc, bi);
        }
    }
}

// ---------------- FFN1 MFMA (swapped): hcl[px][hc] = relu(bn(W1 @ x1)) ----------------
// A = x1cl[px][ci] (rows=px), B = w1b[hc][ci] (cols=hc); D rows=px, cols=hc.
__global__ __launch_bounds__(256) void ffn1_mfma_kernel(const unsigned short* __restrict__ x1cl,
                                                        const unsigned short* __restrict__ w1b,
                                                        const float* __restrict__ s1, const float* __restrict__ b1,
                                                        unsigned short* __restrict__ hcl) {
    int tid = threadIdx.x;
    int w = tid >> 6, lane = tid & 63, g = lane >> 4, l15 = lane & 15;
    int b = blockIdx.z;
    int px0 = blockIdx.x * 256 + w * 64;
    int hc0 = blockIdx.y * 64;
    f32x4 acc[4][4];  // [p][o]
#pragma unroll
    for (int p = 0; p < 4; p++)
#pragma unroll
        for (int o = 0; o < 4; o++)
#pragma unroll
            for (int r = 0; r < 4; r++) acc[p][o][r] = 0.f;
    const unsigned short* xb = x1cl + (((size_t)b * 4096) << 8);
    for (int kc = 0; kc < 8; kc++) {
        bf16x8 Af[4], Bf[4];
#pragma unroll
        for (int p = 0; p < 4; p++)
            Af[p] = *(const bf16x8*)(xb + ((size_t)(px0 + p * 16 + l15) << 8) + kc * 32 + g * 8);
#pragma unroll
        for (int o = 0; o < 4; o++)
            Bf[o] = *(const bf16x8*)(w1b + (size_t)(hc0 + o * 16 + l15) * 256 + kc * 32 + g * 8);
#pragma unroll
        for (int p = 0; p < 4; p++)
#pragma unroll
            for (int o = 0; o < 4; o++)
                acc[p][o] = MFMA16(Af[p], Bf[o], acc[p][o]);
    }
    unsigned short* hb = hcl + (((size_t)b * 4096) << 9);
#pragma unroll
    for (int o = 0; o < 4; o++) {
        int hc = hc0 + o * 16 + l15;
        float sc = s1[hc], bi = b1[hc];
#pragma unroll
        for (int p = 0; p < 4; p++) {
#pragma unroll
            for (int r = 0; r < 4; r++) {
                int px = px0 + p * 16 + 4 * g + r;
                hb[((size_t)px << 9) + hc] = (unsigned short)f2b(fmaxf(fmaf(acc[p][o][r], sc, bi), 0.f));
            }
        }
    }
}

// ---------------- FFN2 MFMA: out += bn(W2 @ h) ----------------
// A = w2b[co][ci], B = hcl[px][ci]; D[co][px]. k=512.
__global__ __launch_bounds__(256) void ffn2_mfma_kernel(const unsigned short* __restrict__ hcl,
                                                        const unsigned short* __restrict__ w2b,
                                                        const float* __restrict__ s2, const float* __restrict__ b2,
                                                        float* __restrict__ out) {
    int tid = threadIdx.x;
    int w = tid >> 6, lane = tid & 63, g = lane >> 4, l15 = lane & 15;
    int b = blockIdx.z;
    int px0 = blockIdx.x * 256 + w * 64;
    int co0 = blockIdx.y * 64;
    f32x4 acc[4][4];
#pragma unroll
    for (int o = 0; o < 4; o++)
#pragma unroll
        for (int p = 0; p < 4; p++)
#pragma unroll
            for (int r = 0; r < 4; r++) acc[o][p][r] = 0.f;
    const unsigned short* hb = hcl + (((size_t)b * 4096) << 9);
    for (int kc = 0; kc < 16; kc++) {
        bf16x8 Af[4], Bf[4];
#pragma unroll
        for (int o = 0; o < 4; o++)
            Af[o] = *(const bf16x8*)(w2b + (size_t)(co0 + o * 16 + l15) * 512 + kc * 32 + g * 8);
#pragma unroll
        for (int p = 0; p < 4; p++)
            Bf[p] = *(const bf16x8*)(hb + ((size_t)(px0 + p * 16 + l15) << 9) + kc * 32 + g * 8);
#pragma unroll
        for (int o = 0; o < 4; o++)
#pragma unroll
            for (int p = 0; p < 4; p++)
                acc[o][p] = MFMA16(Af[o], Bf[p], acc[o][p]);
    }
#pragma unroll
    for (int o = 0; o < 4; o++) {
#pragma unroll
        for (int r = 0; r < 4; r++) {
            int co = co0 + o * 16 + 4 * g + r;
            float sc = s2[co], bi = b2[co];
            size_t base = (((size_t)b * 256 + co) << 12) + px0 + l15;
#pragma unroll
            for (int p = 0; p < 4; p++)
                out[base + p * 16] = out[base + p * 16] + fmaf(acc[o][p][r], sc, bi);
        }
    }
}

extern "C" void kernel_launch(void* const* d_in, const int* in_sizes, int n_in,
                              void* d_out, int out_size, void* d_ws, size_t ws_size,
                              hipStream_t stream) {
    const float* x    = (const float*)d_in[0];
    const float* gn_w = (const float*)d_in[1];
    const float* gn_b = (const float*)d_in[2];
    const float* w_in = (const float*)d_in[3];
    const float* s_in = (const float*)d_in[4];
    const float* b_in = (const float*)d_in[5];
    const float* w_k  = (const float*)d_in[6];
    const float* s_k  = (const float*)d_in[7];
    const float* b_k  = (const float*)d_in[8];
    const float* w_v  = (const float*)d_in[9];
    const float* s_v  = (const float*)d_in[10];
    const float* b_v  = (const float*)d_in[11];
    const float* w_out= (const float*)d_in[12];
    const float* s_out= (const float*)d_in[13];
    const float* b_out= (const float*)d_in[14];
    const float* w1   = (const float*)d_in[15];
    const float* s1   = (const float*)d_in[16];
    const float* b1   = (const float*)d_in[17];
    const float* w2   = (const float*)d_in[18];
    const float* s2   = (const float*)d_in[19];
    const float* b2   = (const float*)d_in[20];
    float* out = (float*)d_out;
    float* ws = (float*)d_ws;

    // float-offset layout (lifetimes verified against launch order):
    float* part = ws;                          // 2048
    float* Aarr = ws + 2048;                   // 4096
    float* Barr = ws + 6144;                   // 4096
    float* t    = ws + 10240;                  // 25165824 f, ends 25176064
    float* a    = ws + 25176064;               // 8388608 f, ends 33564672
    unsigned short* xb   = (unsigned short*)a;               // dead after conv3
    unsigned short* x1cl = (unsigned short*)a;               // written after a is dead (post-acl)
    unsigned short* q_t  = (unsigned short*)(ws + 33564672); // 4194304 sh, dead after attn
    unsigned short* wb   = (unsigned short*)(ws + 35661824); // 884736 sh, dead after conv3
    unsigned short* aucl = (unsigned short*)(ws + 33564672); // 16777216 sh, overlays dead q_t/wb
    unsigned short* hcl  = (unsigned short*)(ws + 33564672); // 33554432 sh, overlays dead aucl; ends 50341888 f
    unsigned short* kd_t = (unsigned short*)(ws + 50341888); // 1048576 sh
    unsigned short* vd_b = (unsigned short*)(ws + 50866176); // 2097152 sh
    unsigned short* wob  = (unsigned short*)(ws + 51914752); // 65536 sh
    unsigned short* w1b  = (unsigned short*)(ws + 51947520); // 131072 sh
    unsigned short* w2b  = (unsigned short*)(ws + 52013056); // 131072 sh, ends 52078592 f

    gn_part_kernel<<<dim3(64, 16), 256, 0, stream>>>(x, part);
    gn_final_kernel<<<16, 256, 0, stream>>>(part, gn_w, gn_b, Aarr, Barr);
    xnb_kernel<<<dim3(64, 16), 256, 0, stream>>>(x, Aarr, Barr, xb);
    wcvt_kernel<<<4736, 256, 0, stream>>>(w_in, w_out, w1, w2, wb, wob, w1b, w2b);
    conv3_mfma_kernel<<<dim3(4, 16, 16), 256, 0, stream>>>(xb, wb, s_in, b_in, t);
    dw_kernel<<<12288, 256, 0, stream>>>(t, w_k, s_k, b_k, w_v, s_v, b_v, kd_t, vd_b);
    qt_kernel<<<dim3(64, 16), 256, 0, stream>>>(t, q_t);
    attn_mfma_kernel<<<dim3(32, 16), 256, 0, stream>>>(q_t, kd_t, vd_b, a);
    acl_kernel<<<dim3(64, 16), 256, 0, stream>>>(a, t, aucl);
    catconv_mfma_kernel<<<dim3(16, 4, 16), 256, 0, stream>>>(aucl, wob, x, s_out, b_out, out);
    x1t_kernel<<<dim3(64, 16), 256, 0, stream>>>(out, x1cl);
    ffn1_mfma_kernel<<<dim3(16, 8, 16), 256, 0, stream>>>(x1cl, w1b, s1, b1, hcl);
    ffn2_mfma_kernel<<<dim3(16, 4, 16), 256, 0, stream>>>(hcl, w2b, s2, b2, out);
}

// Round 5
// 637.367 us; speedup vs baseline: 6.7764x; 1.7306x over previous
//
#include <hip/hip_runtime.h>
#include <hip/hip_bf16.h>

#define DIM 256
#define QK 64
#define PD 128
#define HID 512
#define NPX 4096
#define NB 16
#define SCALE 0.125f
#define GN_EPS 1e-5f

typedef short bf16x8 __attribute__((ext_vector_type(8)));
typedef float f32x4 __attribute__((ext_vector_type(4)));
#define MFMA16(a, b, c) __builtin_amdgcn_mfma_f32_16x16x32_bf16(a, b, c, 0, 0, 0)

__device__ __forceinline__ unsigned f2b(float f) {
    unsigned u = __float_as_uint(f);
    return (u + 0x7fffu + ((u >> 16) & 1u)) >> 16;  // RNE bf16, low 16 bits
}
__device__ __forceinline__ float b2f(unsigned short s) {
    return __uint_as_float((unsigned)s << 16);
}

// ---------------- GroupNorm stats ----------------
__global__ __launch_bounds__(256) void gn_part_kernel(const float* __restrict__ x, float* __restrict__ part) {
    int chunk = blockIdx.x, b = blockIdx.y;
    const float* xp = x + (size_t)b * (DIM * NPX) + (size_t)chunk * 16384;
    float s = 0.f, ss = 0.f;
    for (int i = threadIdx.x; i < 16384; i += 256) { float v = xp[i]; s += v; ss += v * v; }
    for (int off = 32; off > 0; off >>= 1) { s += __shfl_down(s, off); ss += __shfl_down(ss, off); }
    __shared__ float red[8];
    int w = threadIdx.x >> 6;
    if ((threadIdx.x & 63) == 0) { red[w * 2] = s; red[w * 2 + 1] = ss; }
    __syncthreads();
    if (threadIdx.x == 0) {
        float S = red[0] + red[2] + red[4] + red[6];
        float SS = red[1] + red[3] + red[5] + red[7];
        part[(b * 64 + chunk) * 2] = S;
        part[(b * 64 + chunk) * 2 + 1] = SS;
    }
}

__global__ __launch_bounds__(256) void gn_final_kernel(const float* __restrict__ part,
                                                       const float* __restrict__ gn_w, const float* __restrict__ gn_b,
                                                       float* __restrict__ Aarr, float* __restrict__ Barr) {
    int b = blockIdx.x;
    float s = 0.f, ss = 0.f;
    if (threadIdx.x < 64) {
        s = part[(b * 64 + threadIdx.x) * 2];
        ss = part[(b * 64 + threadIdx.x) * 2 + 1];
        for (int off = 32; off > 0; off >>= 1) { s += __shfl_down(s, off); ss += __shfl_down(ss, off); }
    }
    __shared__ float sh[2];
    if (threadIdx.x == 0) {
        const float invN = 1.f / (float)(DIM * NPX);
        float mu = s * invN;
        float var = ss * invN - mu * mu;
        sh[0] = mu; sh[1] = rsqrtf(var + GN_EPS);
    }
    __syncthreads();
    float mu = sh[0], rstd = sh[1];
    int c = threadIdx.x;
    float g = gn_w[c] * rstd;
    Aarr[b * 256 + c] = g;
    Barr[b * 256 + c] = gn_b[c] - mu * g;
}

// ---------------- xn -> bf16 channels-last [B][64][64][256] ----------------
__global__ __launch_bounds__(256) void xnb_kernel(const float* __restrict__ x,
                                                  const float* __restrict__ Aarr, const float* __restrict__ Barr,
                                                  unsigned short* __restrict__ xb) {
    int y = blockIdx.x, b = blockIdx.y;
    int tid = threadIdx.x;
    __shared__ unsigned short tile[64 * 264];
    const float* xr = x + ((size_t)b << 20) + (size_t)y * 64;
    const float* Ab = Aarr + b * 256;
    const float* Bb = Barr + b * 256;
    for (int it = 0; it < 64; it++) {
        int lin = it * 256 + tid;
        int c = lin >> 6, px = lin & 63;
        float v = fmaf(xr[((size_t)c << 12) + px], Ab[c], Bb[c]);
        tile[px * 264 + c] = (unsigned short)f2b(v);
    }
    __syncthreads();
    unsigned short* ob = xb + (((size_t)(b * 64 + y)) << 14);
    for (int it = 0; it < 8; it++) {
        int lin = it * 256 + tid;
        int px = lin >> 5, g = lin & 31;
        *(uint4*)&ob[px * 256 + g * 8] = *(const uint4*)&tile[px * 264 + g * 8];
    }
}

// ---------------- weights -> bf16 ----------------
// wb2: frag-major [ck 8][tap 9][oc 384][ci 32]; wob/w1b/w2b: [O][I]
__global__ __launch_bounds__(256) void wcvt_kernel(const float* __restrict__ w_in, const float* __restrict__ w_out,
                                                   const float* __restrict__ w1, const float* __restrict__ w2,
                                                   unsigned short* __restrict__ wb2, unsigned short* __restrict__ wob,
                                                   unsigned short* __restrict__ w1b, unsigned short* __restrict__ w2b) {
    int idx = blockIdx.x * 256 + threadIdx.x;
    if (idx < 884736) {
        int ci = idx & 31;
        int oc = (idx >> 5) % 384;
        int tapck = idx / 12288;           // 384*32
        int ck = tapck / 9, tap = tapck % 9;
        wb2[idx] = (unsigned short)f2b(w_in[((size_t)oc * 256 + ck * 32 + ci) * 9 + tap]);
    } else if (idx < 950272) {
        int j = idx - 884736;
        wob[j] = (unsigned short)f2b(w_out[j]);
    } else if (idx < 1081344) {
        int j = idx - 950272;
        w1b[j] = (unsigned short)f2b(w1[j]);
    } else if (idx < 1212416) {
        int j = idx - 1081344;
        w2b[j] = (unsigned short)f2b(w2[j]);
    }
}

// ---------------- conv3x3 implicit-GEMM MFMA -> tcl [b][px][384] bf16 ----------------
// block: 4 waves, tile 64 oc x (4 rows x 64 px); wave w -> image row y0+w.
__global__ __launch_bounds__(256, 4) void conv3_mfma_kernel(const unsigned short* __restrict__ xb,
                                                            const unsigned short* __restrict__ wb2,
                                                            const float* __restrict__ s_in, const float* __restrict__ b_in,
                                                            unsigned short* __restrict__ tcl) {
    int ocb = blockIdx.x, rg = blockIdx.y, b = blockIdx.z;
    int tid = threadIdx.x;
    int w = tid >> 6, lane = tid & 63, g = lane >> 4, l15 = lane & 15;
    __shared__ unsigned short xs[6 * 66 * 40];
    int oc0 = ocb * 64, y0 = rg * 4;
    f32x4 acc[4][4];
#pragma unroll
    for (int o = 0; o < 4; o++)
#pragma unroll
        for (int p = 0; p < 4; p++)
#pragma unroll
            for (int r = 0; r < 4; r++) acc[o][p][r] = 0.f;
    if (tid < 48) {
        int row = tid >> 3, cp = (tid >> 2) & 1, gg = tid & 3;
        int col = cp ? 65 : 0;
        *(uint4*)&xs[(row * 66 + col) * 40 + gg * 8] = make_uint4(0, 0, 0, 0);
    }
    const unsigned short* xg = xb + ((size_t)b << 20);  // [64][64][256]
    for (int ck = 0; ck < 8; ck++) {
        int ci0 = ck * 32;
        __syncthreads();
#pragma unroll
        for (int it = 0; it < 6; it++) {
            int lin = it * 256 + tid;
            int gg = lin & 3, col = (lin >> 2) & 63, row = lin >> 8;
            int y = y0 - 1 + row;
            uint4 val = make_uint4(0, 0, 0, 0);
            if (y >= 0 && y < 64)
                val = *(const uint4*)(xg + (((size_t)(y * 64 + col)) << 8) + ci0 + gg * 8);
            *(uint4*)&xs[(row * 66 + col + 1) * 40 + gg * 8] = val;
        }
        __syncthreads();
        const unsigned short* wp = wb2 + (size_t)ck * 9 * 384 * 32;
#pragma unroll
        for (int tap = 0; tap < 9; tap++) {
            int dy = tap / 3, dx = tap % 3;
            bf16x8 Af[4], Bf[4];
#pragma unroll
            for (int o = 0; o < 4; o++)
                Af[o] = *(const bf16x8*)(wp + ((size_t)tap * 384 + oc0 + o * 16 + l15) * 32 + g * 8);
#pragma unroll
            for (int p = 0; p < 4; p++)
                Bf[p] = *(const bf16x8*)&xs[((w + dy) * 66 + p * 16 + l15 + dx) * 40 + g * 8];
#pragma unroll
            for (int o = 0; o < 4; o++)
#pragma unroll
                for (int p = 0; p < 4; p++)
                    acc[o][p] = MFMA16(Af[o], Bf[p], acc[o][p]);
        }
    }
    int y = y0 + w;
    unsigned short* tout = tcl + ((size_t)(b * 4096 + y * 64)) * 384;
#pragma unroll
    for (int o = 0; o < 4; o++) {
        int ocb4 = oc0 + o * 16 + 4 * g;
        float s0 = s_in[ocb4], s1 = s_in[ocb4 + 1], s2 = s_in[ocb4 + 2], s3 = s_in[ocb4 + 3];
        float b0 = b_in[ocb4], b1 = b_in[ocb4 + 1], b2 = b_in[ocb4 + 2], b3 = b_in[ocb4 + 3];
#pragma unroll
        for (int p = 0; p < 4; p++) {
            ushort4 h;
            h.x = (unsigned short)f2b(fmaf(acc[o][p][0], s0, b0));
            h.y = (unsigned short)f2b(fmaf(acc[o][p][1], s1, b1));
            h.z = (unsigned short)f2b(fmaf(acc[o][p][2], s2, b2));
            h.w = (unsigned short)f2b(fmaf(acc[o][p][3], s3, b3));
            *(ushort4*)&tout[(size_t)(p * 16 + l15) * 384 + ocb4] = h;
        }
    }
}

// ---------------- depthwise 2x2 stride-2 (reads tcl) ----------------
// kd_t: [B][1024 m][64 c] bf16 ; vd_b: [B][128 p][1024 m] bf16
__global__ __launch_bounds__(256) void dw_kernel(const unsigned short* __restrict__ tcl,
                                                 const float* __restrict__ w_k, const float* __restrict__ s_k, const float* __restrict__ b_k,
                                                 const float* __restrict__ w_v, const float* __restrict__ s_v, const float* __restrict__ b_v,
                                                 unsigned short* __restrict__ kd_t, unsigned short* __restrict__ vd_b) {
    int gid = blockIdx.x * 256 + threadIdx.x;
    if (gid < (1 << 20)) {
        int b = gid >> 16, c = (gid >> 10) & 63, m = gid & 1023;
        int yo = m >> 5, xo = m & 31;
        const unsigned short* src = tcl + ((size_t)(b * 4096 + yo * 128 + xo * 2)) * 384 + 64 + c;
        float v = w_k[c * 4] * b2f(src[0]) + w_k[c * 4 + 1] * b2f(src[384]) +
                  w_k[c * 4 + 2] * b2f(src[24576]) + w_k[c * 4 + 3] * b2f(src[24960]);
        kd_t[((size_t)(b * 1024 + m) << 6) + c] = (unsigned short)f2b(fmaf(v, s_k[c], b_k[c]));
    } else {
        int gg = gid - (1 << 20);
        int b = gg >> 17, c = (gg >> 10) & 127, m = gg & 1023;
        int yo = m >> 5, xo = m & 31;
        const unsigned short* src = tcl + ((size_t)(b * 4096 + yo * 128 + xo * 2)) * 384 + 128 + c;
        float v = w_v[c * 4] * b2f(src[0]) + w_v[c * 4 + 1] * b2f(src[384]) +
                  w_v[c * 4 + 2] * b2f(src[24576]) + w_v[c * 4 + 3] * b2f(src[24960]);
        vd_b[gg] = (unsigned short)f2b(fmaf(v, s_v[c], b_v[c]));
    }
}

// ---------------- MFMA flash attention (q read from tcl, stride 384) ----------------
__global__ __launch_bounds__(256) void attn_mfma_kernel(const unsigned short* __restrict__ tcl,
                                                        const unsigned short* __restrict__ kd_t,
                                                        const unsigned short* __restrict__ vd_b,
                                                        float* __restrict__ a_out) {
    int tid = threadIdx.x;
    int wid = tid >> 6, lane = tid & 63;
    int g = lane >> 4, l15 = lane & 15;
    int b = blockIdx.y;
    int n0 = (blockIdx.x * 4 + wid) * 32;

    bf16x8 qf[2][2];
#pragma unroll
    for (int nf = 0; nf < 2; nf++)
#pragma unroll
        for (int kc = 0; kc < 2; kc++)
            qf[nf][kc] = *(const bf16x8*)(tcl + ((size_t)(b * 4096 + n0 + 16 * nf + l15)) * 384 + kc * 32 + g * 8);

    f32x4 O[8][2];
#pragma unroll
    for (int pt = 0; pt < 8; pt++)
#pragma unroll
        for (int nf = 0; nf < 2; nf++)
#pragma unroll
            for (int r = 0; r < 4; r++) O[pt][nf][r] = 0.f;
    float mr[2] = {-1e30f, -1e30f}, lr[2] = {0.f, 0.f};

    const unsigned short* kb = kd_t + ((size_t)b << 16);
    const unsigned short* vb = vd_b + ((size_t)(b * 128) << 10);

    union BU { unsigned u[4]; bf16x8 v; };

    for (int mt = 0; mt < 16; mt++) {
        int m0 = mt * 64;
        f32x4 sp[4][2];
#pragma unroll
        for (int f = 0; f < 4; f++)
#pragma unroll
            for (int nf = 0; nf < 2; nf++)
#pragma unroll
                for (int r = 0; r < 4; r++) sp[f][nf][r] = 0.f;
#pragma unroll
        for (int f = 0; f < 4; f++) {
#pragma unroll
            for (int kc = 0; kc < 2; kc++) {
                bf16x8 kf = *(const bf16x8*)(kb + (((size_t)(m0 + 16 * f + l15)) << 6) + kc * 32 + g * 8);
                sp[f][0] = MFMA16(kf, qf[0][kc], sp[f][0]);
                sp[f][1] = MFMA16(kf, qf[1][kc], sp[f][1]);
            }
        }
        BU Bp[2][2];
        int srcA = l15 + ((g & 1) << 5);
        int srcB = srcA + 16;
        bool hi = (g >> 1) != 0;
#pragma unroll
        for (int nf = 0; nf < 2; nf++) {
            float tmax = -1e30f;
#pragma unroll
            for (int f = 0; f < 4; f++)
#pragma unroll
                for (int r = 0; r < 4; r++) tmax = fmaxf(tmax, sp[f][nf][r]);
            tmax = fmaxf(tmax, __shfl_xor(tmax, 16));
            tmax = fmaxf(tmax, __shfl_xor(tmax, 32));
            float newm = fmaxf(mr[nf], tmax * SCALE);
            float fac = __expf(mr[nf] - newm);
            float ps = 0.f;
            unsigned pl[4], ph[4];
#pragma unroll
            for (int f = 0; f < 4; f++) {
                float p0 = __expf(fmaf(sp[f][nf][0], SCALE, -newm));
                float p1 = __expf(fmaf(sp[f][nf][1], SCALE, -newm));
                float p2 = __expf(fmaf(sp[f][nf][2], SCALE, -newm));
                float p3 = __expf(fmaf(sp[f][nf][3], SCALE, -newm));
                ps += (p0 + p1) + (p2 + p3);
                pl[f] = f2b(p0) | (f2b(p1) << 16);
                ph[f] = f2b(p2) | (f2b(p3) << 16);
            }
            ps += __shfl_xor(ps, 16);
            ps += __shfl_xor(ps, 32);
            lr[nf] = fmaf(lr[nf], fac, ps);
            mr[nf] = newm;
#pragma unroll
            for (int pt = 0; pt < 8; pt++)
#pragma unroll
                for (int r = 0; r < 4; r++) O[pt][nf][r] *= fac;
#pragma unroll
            for (int kc = 0; kc < 2; kc++) {
                unsigned a0 = (unsigned)__shfl((int)pl[2 * kc], srcA);
                unsigned a1 = (unsigned)__shfl((int)ph[2 * kc], srcA);
                unsigned b0 = (unsigned)__shfl((int)pl[2 * kc + 1], srcA);
                unsigned b1 = (unsigned)__shfl((int)ph[2 * kc + 1], srcA);
                unsigned a2 = (unsigned)__shfl((int)pl[2 * kc], srcB);
                unsigned a3 = (unsigned)__shfl((int)ph[2 * kc], srcB);
                unsigned b2 = (unsigned)__shfl((int)pl[2 * kc + 1], srcB);
                unsigned b3 = (unsigned)__shfl((int)ph[2 * kc + 1], srcB);
                Bp[nf][kc].u[0] = hi ? b0 : a0;
                Bp[nf][kc].u[1] = hi ? b1 : a1;
                Bp[nf][kc].u[2] = hi ? b2 : a2;
                Bp[nf][kc].u[3] = hi ? b3 : a3;
            }
        }
#pragma unroll
        for (int pt = 0; pt < 8; pt++) {
#pragma unroll
            for (int kc = 0; kc < 2; kc++) {
                bf16x8 vf = *(const bf16x8*)(vb + (((size_t)(pt * 16 + l15)) << 10) + m0 + kc * 32 + g * 8);
                O[pt][0] = MFMA16(vf, Bp[0][kc].v, O[pt][0]);
                O[pt][1] = MFMA16(vf, Bp[1][kc].v, O[pt][1]);
            }
        }
    }
    float inv0 = 1.f / lr[0], inv1 = 1.f / lr[1];
#pragma unroll
    for (int pt = 0; pt < 8; pt++) {
#pragma unroll
        for (int r = 0; r < 4; r++) {
            int prow = pt * 16 + 4 * g + r;
            size_t base = (((size_t)(b * 128 + prow)) << 12) + n0 + l15;
            a_out[base] = O[pt][0][r] * inv0;
            a_out[base + 16] = O[pt][1][r] * inv1;
        }
    }
}

// ---------------- acl: relu(cat(a,u)) -> aucl [B][4096][256] bf16 ----------------
__global__ __launch_bounds__(256) void acl_kernel(const float* __restrict__ a_in, const unsigned short* __restrict__ tcl,
                                                  unsigned short* __restrict__ aucl) {
    int ng = blockIdx.x, b = blockIdx.y;
    int tid = threadIdx.x;
    __shared__ unsigned short tile[64 * 132];
    int n0 = ng * 64;
    int nl = tid & 63, c4 = tid >> 6;
    // a-part: transpose [128 ch][64 px] fp32 -> [px][128] bf16 with relu
    for (int it = 0; it < 32; it++) {
        int ci = it * 4 + c4;
        float v = a_in[(((size_t)b * 128 + ci) << 12) + n0 + nl];
        tile[nl * 132 + ci] = (unsigned short)f2b(fmaxf(v, 0.f));
    }
    __syncthreads();
    for (int it = 0; it < 4; it++) {
        int lin = it * 256 + tid;
        int n = lin >> 4, cg = lin & 15;
        *(uint4*)&aucl[((size_t)(b * 4096 + n0 + n)) * 256 + cg * 8] = *(const uint4*)&tile[n * 132 + cg * 8];
    }
    // u-part: direct bf16 relu copy from tcl[px][256..383]
    for (int it = 0; it < 4; it++) {
        int lin = it * 256 + tid;
        int n = lin >> 4, cg = lin & 15;
        bf16x8 v = *(const bf16x8*)(tcl + ((size_t)(b * 4096 + n0 + n)) * 384 + 256 + cg * 8);
#pragma unroll
        for (int j = 0; j < 8; j++) {
            unsigned short s = (unsigned short)v[j];
            v[j] = (short)((s & 0x8000u) ? 0 : s);
        }
        *(bf16x8*)(aucl + ((size_t)(b * 4096 + n0 + n)) * 256 + 128 + cg * 8) = v;
    }
}

// ---------------- catconv MFMA: out = x + bn(W_out @ relu(cat)); also emits x1cl bf16 ----------------
__global__ __launch_bounds__(256) void catconv_mfma_kernel(const unsigned short* __restrict__ aucl,
                                                           const unsigned short* __restrict__ wob,
                                                           const float* __restrict__ x,
                                                           const float* __restrict__ s_out, const float* __restrict__ b_out,
                                                           float* __restrict__ out, unsigned short* __restrict__ x1cl) {
    int tid = threadIdx.x;
    int w = tid >> 6, lane = tid & 63, g = lane >> 4, l15 = lane & 15;
    int b = blockIdx.z;
    int px0 = blockIdx.x * 256 + w * 64;
    int co0 = blockIdx.y * 64;
    f32x4 acc[4][4];
#pragma unroll
    for (int o = 0; o < 4; o++)
#pragma unroll
        for (int p = 0; p < 4; p++)
#pragma unroll
            for (int r = 0; r < 4; r++) acc[o][p][r] = 0.f;
    const unsigned short* ab = aucl + (((size_t)b * 4096) << 8);
    for (int kc = 0; kc < 8; kc++) {
        bf16x8 Af[4], Bf[4];
#pragma unroll
        for (int o = 0; o < 4; o++)
            Af[o] = *(const bf16x8*)(wob + (size_t)(co0 + o * 16 + l15) * 256 + kc * 32 + g * 8);
#pragma unroll
        for (int p = 0; p < 4; p++)
            Bf[p] = *(const bf16x8*)(ab + ((size_t)(px0 + p * 16 + l15) << 8) + kc * 32 + g * 8);
#pragma unroll
        for (int o = 0; o < 4; o++)
#pragma unroll
            for (int p = 0; p < 4; p++)
                acc[o][p] = MFMA16(Af[o], Bf[p], acc[o][p]);
    }
#pragma unroll
    for (int o = 0; o < 4; o++) {
        int co_b = co0 + o * 16 + 4 * g;
#pragma unroll
        for (int r = 0; r < 4; r++) {
            int co = co_b + r;
            float sc = s_out[co], bi = b_out[co];
            size_t base = (((size_t)b * 256 + co) << 12) + px0 + l15;
#pragma unroll
            for (int p = 0; p < 4; p++) {
                float res = x[base + p * 16] + fmaf(acc[o][p][r], sc, bi);
                out[base + p * 16] = res;
                acc[o][p][r] = res;
            }
        }
#pragma unroll
        for (int p = 0; p < 4; p++) {
            ushort4 h;
            h.x = (unsigned short)f2b(acc[o][p][0]);
            h.y = (unsigned short)f2b(acc[o][p][1]);
            h.z = (unsigned short)f2b(acc[o][p][2]);
            h.w = (unsigned short)f2b(acc[o][p][3]);
            *(ushort4*)&x1cl[((size_t)(b * 4096 + px0 + p * 16 + l15)) * 256 + co_b] = h;
        }
    }
}

// ---------------- FFN1 MFMA (swapped): hcl[px][hc] = relu(bn(W1 @ x1)) ----------------
__global__ __launch_bounds__(256) void ffn1_mfma_kernel(const unsigned short* __restrict__ x1cl,
                                                        const unsigned short* __restrict__ w1b,
                                                        const float* __restrict__ s1, const float* __restrict__ b1,
                                                        unsigned short* __restrict__ hcl) {
    int tid = threadIdx.x;
    int w = tid >> 6, lane = tid & 63, g = lane >> 4, l15 = lane & 15;
    int b = blockIdx.z;
    int px0 = blockIdx.x * 256 + w * 64;
    int hc0 = blockIdx.y * 64;
    f32x4 acc[4][4];  // [p][o]
#pragma unroll
    for (int p = 0; p < 4; p++)
#pragma unroll
        for (int o = 0; o < 4; o++)
#pragma unroll
            for (int r = 0; r < 4; r++) acc[p][o][r] = 0.f;
    const unsigned short* xb = x1cl + (((size_t)b * 4096) << 8);
    for (int kc = 0; kc < 8; kc++) {
        bf16x8 Af[4], Bf[4];
#pragma unroll
        for (int p = 0; p < 4; p++)
            Af[p] = *(const bf16x8*)(xb + ((size_t)(px0 + p * 16 + l15) << 8) + kc * 32 + g * 8);
#pragma unroll
        for (int o = 0; o < 4; o++)
            Bf[o] = *(const bf16x8*)(w1b + (size_t)(hc0 + o * 16 + l15) * 256 + kc * 32 + g * 8);
#pragma unroll
        for (int p = 0; p < 4; p++)
#pragma unroll
            for (int o = 0; o < 4; o++)
                acc[p][o] = MFMA16(Af[p], Bf[o], acc[p][o]);
    }
    unsigned short* hb = hcl + (((size_t)b * 4096) << 9);
#pragma unroll
    for (int o = 0; o < 4; o++) {
        int hc = hc0 + o * 16 + l15;
        float sc = s1[hc], bi = b1[hc];
#pragma unroll
        for (int p = 0; p < 4; p++) {
#pragma unroll
            for (int r = 0; r < 4; r++) {
                int px = px0 + p * 16 + 4 * g + r;
                hb[((size_t)px << 9) + hc] = (unsigned short)f2b(fmaxf(fmaf(acc[p][o][r], sc, bi), 0.f));
            }
        }
    }
}

// ---------------- FFN2 MFMA: out += bn(W2 @ h) ----------------
__global__ __launch_bounds__(256) void ffn2_mfma_kernel(const unsigned short* __restrict__ hcl,
                                                        const unsigned short* __restrict__ w2b,
                                                        const float* __restrict__ s2, const float* __restrict__ b2,
                                                        float* __restrict__ out) {
    int tid = threadIdx.x;
    int w = tid >> 6, lane = tid & 63, g = lane >> 4, l15 = lane & 15;
    int b = blockIdx.z;
    int px0 = blockIdx.x * 256 + w * 64;
    int co0 = blockIdx.y * 64;
    f32x4 acc[4][4];
#pragma unroll
    for (int o = 0; o < 4; o++)
#pragma unroll
        for (int p = 0; p < 4; p++)
#pragma unroll
            for (int r = 0; r < 4; r++) acc[o][p][r] = 0.f;
    const unsigned short* hb = hcl + (((size_t)b * 4096) << 9);
    for (int kc = 0; kc < 16; kc++) {
        bf16x8 Af[4], Bf[4];
#pragma unroll
        for (int o = 0; o < 4; o++)
            Af[o] = *(const bf16x8*)(w2b + (size_t)(co0 + o * 16 + l15) * 512 + kc * 32 + g * 8);
#pragma unroll
        for (int p = 0; p < 4; p++)
            Bf[p] = *(const bf16x8*)(hb + ((size_t)(px0 + p * 16 + l15) << 9) + kc * 32 + g * 8);
#pragma unroll
        for (int o = 0; o < 4; o++)
#pragma unroll
            for (int p = 0; p < 4; p++)
                acc[o][p] = MFMA16(Af[o], Bf[p], acc[o][p]);
    }
#pragma unroll
    for (int o = 0; o < 4; o++) {
#pragma unroll
        for (int r = 0; r < 4; r++) {
            int co = co0 + o * 16 + 4 * g + r;
            float sc = s2[co], bi = b2[co];
            size_t base = (((size_t)b * 256 + co) << 12) + px0 + l15;
#pragma unroll
            for (int p = 0; p < 4; p++)
                out[base + p * 16] = out[base + p * 16] + fmaf(acc[o][p][r], sc, bi);
        }
    }
}

extern "C" void kernel_launch(void* const* d_in, const int* in_sizes, int n_in,
                              void* d_out, int out_size, void* d_ws, size_t ws_size,
                              hipStream_t stream) {
    const float* x    = (const float*)d_in[0];
    const float* gn_w = (const float*)d_in[1];
    const float* gn_b = (const float*)d_in[2];
    const float* w_in = (const float*)d_in[3];
    const float* s_in = (const float*)d_in[4];
    const float* b_in = (const float*)d_in[5];
    const float* w_k  = (const float*)d_in[6];
    const float* s_k  = (const float*)d_in[7];
    const float* b_k  = (const float*)d_in[8];
    const float* w_v  = (const float*)d_in[9];
    const float* s_v  = (const float*)d_in[10];
    const float* b_v  = (const float*)d_in[11];
    const float* w_out= (const float*)d_in[12];
    const float* s_out= (const float*)d_in[13];
    const float* b_out= (const float*)d_in[14];
    const float* w1   = (const float*)d_in[15];
    const float* s1   = (const float*)d_in[16];
    const float* b1   = (const float*)d_in[17];
    const float* w2   = (const float*)d_in[18];
    const float* s2   = (const float*)d_in[19];
    const float* b2   = (const float*)d_in[20];
    float* out = (float*)d_out;
    float* ws = (float*)d_ws;

    // float-offset layout; lifetimes checked against launch order:
    float* part = ws;                           // 2048
    float* Aarr = ws + 2048;
    float* Barr = ws + 6144;                    // end 10240
    unsigned short* tcl = (unsigned short*)(ws + 10240);       // 16*4096*384 sh = 12,582,912 f -> end 12,593,152
    float* a = ws + 12593152;                   // 8,388,608 f -> end 20,981,760
    unsigned short* xb   = (unsigned short*)a;                 // alias: dead after conv3; a written by attn later
    unsigned short* x1cl = (unsigned short*)a;                 // alias: written by catconv after a is dead (post-acl)
    unsigned short* aucl = (unsigned short*)(ws + 20981760);   // 16,777,216 sh = 8,388,608 f -> end 29,370,368
    unsigned short* hcl  = (unsigned short*)(ws + 20981760);   // 33,554,432 sh; overlays dead aucl -> end 37,758,976
    unsigned short* kd_t = (unsigned short*)(ws + 37758976);   // 1,048,576 sh -> end 38,283,264
    unsigned short* vd_b = (unsigned short*)(ws + 38283264);   // 2,097,152 sh -> end 39,331,840
    unsigned short* wb2  = (unsigned short*)(ws + 39331840);   // 884,736 sh -> end 39,774,208
    unsigned short* wob  = (unsigned short*)(ws + 39774208);   // 65,536 sh
    unsigned short* w1b  = (unsigned short*)(ws + 39806976);   // 131,072 sh
    unsigned short* w2b  = (unsigned short*)(ws + 39872512);   // 131,072 sh -> end 39,938,048

    gn_part_kernel<<<dim3(64, 16), 256, 0, stream>>>(x, part);
    gn_final_kernel<<<16, 256, 0, stream>>>(part, gn_w, gn_b, Aarr, Barr);
    xnb_kernel<<<dim3(64, 16), 256, 0, stream>>>(x, Aarr, Barr, xb);
    wcvt_kernel<<<4736, 256, 0, stream>>>(w_in, w_out, w1, w2, wb2, wob, w1b, w2b);
    conv3_mfma_kernel<<<dim3(6, 16, 16), 256, 0, stream>>>(xb, wb2, s_in, b_in, tcl);
    dw_kernel<<<12288, 256, 0, stream>>>(tcl, w_k, s_k, b_k, w_v, s_v, b_v, kd_t, vd_b);
    attn_mfma_kernel<<<dim3(32, 16), 256, 0, stream>>>(tcl, kd_t, vd_b, a);
    acl_kernel<<<dim3(64, 16), 256, 0, stream>>>(a, tcl, aucl);
    catconv_mfma_kernel<<<dim3(16, 4, 16), 256, 0, stream>>>(aucl, wob, x, s_out, b_out, out, x1cl);
    ffn1_mfma_kernel<<<dim3(16, 8, 16), 256, 0, stream>>>(x1cl, w1b, s1, b1, hcl);
    ffn2_mfma_kernel<<<dim3(16, 4, 16), 256, 0, stream>>>(hcl, w2b, s2, b2, out);
}